// Round 9
// baseline (1191.366 us; speedup 1.0000x reference)
//
#include <hip/hip_runtime.h>

#define TLEN 8249
#define TPAD 8320          // 52*160
#define NTILES_C 130       // causal tiles (M=64)
#define NTILES_P 52        // persistent tiles (M=160)
#define NBLK (NTILES_P*NB) // 208 persistent blocks
#define NB 4
#define NAUX 54
#define NQ 256
#define HID 192
#define NSKIP 256
#define KW 6
#define UPF 110
#define TAUX 75
#define PADR 180           // 5*36 max left reach of dilated conv
#define HROWS (PADR + TPAD)

typedef __attribute__((ext_vector_type(8))) short bf16x8v;
typedef __attribute__((ext_vector_type(4))) float f32x4;

__device__ __forceinline__ unsigned short f2bf(float f) {
  unsigned int u = __float_as_uint(f);
  u += 0x7FFFu + ((u >> 16) & 1u);   // RNE
  return (unsigned short)(u >> 16);
}

__device__ __forceinline__ f32x4 mfma16(bf16x8v a, bf16x8v b, f32x4 c) {
  return __builtin_amdgcn_mfma_f32_16x16x32_bf16(a, b, c, 0, 0, 0);
}

// device-scope phase barrier (monotonic counter; cnt zeroed per launch)
__device__ __forceinline__ void gridbar(unsigned int* cnt, unsigned int target, int tid) {
  __syncthreads();
  if (tid == 0) {
    __threadfence();   // release: cross-XCD L2 writeback
    __hip_atomic_fetch_add(cnt, 1u, __ATOMIC_ACQ_REL, __HIP_MEMORY_SCOPE_AGENT);
    while (__hip_atomic_load(cnt, __ATOMIC_ACQUIRE, __HIP_MEMORY_SCOPE_AGENT) < target)
      __builtin_amdgcn_s_sleep(2);
    __threadfence();   // acquire: invalidate stale L1/L2
  }
  __syncthreads();
}

// ---------------- weight prepack (MFMA fragment order) + C vector ----------
__global__ void prepack_kernel(
    const float* causal_w, const float* dilh_w, const float* skip_w,
    const float* out1_w, const float* out2_w,
    const float* inx_w, const float* inx_b, const float* up_b,
    unsigned short* pk_causal, unsigned short* pk_dilh, unsigned short* pk_skip,
    unsigned short* pk_out1, unsigned short* pk_out2, float* Cbuf)
{
  int i = blockIdx.x * blockDim.x + threadIdx.x;
  if (i < 9*6*6*24*64*8) {            // dilh: [l][tap][kc6][nf24][lane][8]
    int t = i;
    int j = t & 7; t >>= 3;
    int lane = t & 63; t >>= 6;
    int nf = t % 24; t /= 24;
    int kc = t % 6; t /= 6;
    int tap = t % 6; t /= 6;
    int l = t;
    int oc = nf*16 + (lane & 15);
    int ic = kc*32 + ((lane >> 4) << 3) + j;
    pk_dilh[i] = f2bf(dilh_w[((l*384 + oc)*HID + ic)*KW + tap]);
  }
  if (i < 6*8*12*64*8) {              // causal: [tap][kc8][nf12][lane][8]
    int t = i;
    int j = t & 7; t >>= 3;
    int lane = t & 63; t >>= 6;
    int nf = t % 12; t /= 12;
    int kc = t % 8; t /= 8;
    int tap = t;
    int oc = nf*16 + (lane & 15);
    int ic = kc*32 + ((lane >> 4) << 3) + j;
    pk_causal[i] = f2bf(causal_w[(oc*NQ + ic)*KW + tap]);
  }
  if (i < 9*6*16*64*8) {              // skip: [l][kc6][nf16][lane][8]
    int t = i;
    int j = t & 7; t >>= 3;
    int lane = t & 63; t >>= 6;
    int nf = t % 16; t /= 16;
    int kc = t % 6; t /= 6;
    int l = t;
    int sc = nf*16 + (lane & 15);
    int ic = kc*32 + ((lane >> 4) << 3) + j;
    pk_skip[i] = f2bf(skip_w[(l*NSKIP + sc)*HID + ic]);
  }
  if (i < 8*16*64*8) {                // out1/out2: [kc8][nf16][lane][8]
    int t = i;
    int j = t & 7; t >>= 3;
    int lane = t & 63; t >>= 6;
    int nf = t % 16; t /= 16;
    int kc = t;
    int oq = nf*16 + (lane & 15);
    int sc = kc*32 + ((lane >> 4) << 3) + j;
    pk_out1[i] = f2bf(out1_w[oq*NSKIP + sc]);
    pk_out2[i] = f2bf(out2_w[oq*NQ + sc]);
  }
  if (i < 9*384) {                    // C[l][oc] = up_b*rowsum(inx_w)+inx_b
    int l = i / 384, oc = i % 384;
    const float* wr = inx_w + (l*384 + oc)*486;
    float s = 0.f;
    for (int c = 0; c < 486; c++) s += wr[c];
    Cbuf[i] = up_b[0]*s + inx_b[i];
  }
}

// ---------------- zero the 180-row causal pads of both slabs ---------------
__global__ void zpad_kernel(unsigned short* s0, unsigned short* s1) {
  int i = blockIdx.x*blockDim.x + threadIdx.x;
  if (i < NB*PADR*HID) {
    int b = i / (PADR*HID), rr = i % (PADR*HID);
    s0[(size_t)b*HROWS*HID + rr] = 0;
    s1[(size_t)b*HROWS*HID + rr] = 0;
  }
}

// ---------------- tiny aux chain (all fp32) --------------------------------
__global__ void aux1_kernel(const float* aux, const float* w, const float* bias, float* a1) {
  int q = blockIdx.x, b = blockIdx.y, co = threadIdx.x;
  if (co >= NAUX) return;
  float acc = bias[co];
  for (int ci = 0; ci < NAUX; ci++)
    acc += w[co*NAUX + ci] * aux[(b*NAUX + ci)*TAUX + q];
  a1[(b*NAUX + co)*TAUX + q] = acc;
}

__global__ void aux2_kernel(const float* a1, const float* w, const float* bias, float* a2) {
  __shared__ float s[3][NAUX];
  int q = blockIdx.x, b = blockIdx.y, tid = threadIdx.x;
  for (int i = tid; i < 3*NAUX; i += blockDim.x) {
    int k = i / NAUX, c = i % NAUX;
    int qq = q - 1 + k;
    s[k][c] = (qq >= 0 && qq < TAUX) ? a1[(b*NAUX + c)*TAUX + qq] : 0.f;
  }
  __syncthreads();
  int co = tid;
  if (co >= 162) return;
  float acc = bias[co];
  for (int c = 0; c < NAUX; c++)
    #pragma unroll
    for (int k = 0; k < 3; k++)
      acc += w[(co*NAUX + c)*3 + k] * s[k][c];
  a2[(b*162 + co)*TAUX + q] = acc;
}

__global__ void aux3_kernel(const float* a2, const float* w, const float* bias, float* a3) {
  __shared__ float s[3][162];
  int q = blockIdx.x, b = blockIdx.y, tid = threadIdx.x;
  for (int i = tid; i < 3*162; i += blockDim.x) {
    int k = i / 162, c = i % 162;
    int qq = q + 3*(k - 1);
    s[k][c] = (qq >= 0 && qq < TAUX) ? a2[(b*162 + c)*TAUX + qq] : 0.f;
  }
  __syncthreads();
  int co = tid;
  if (co >= 486) return;
  float acc = bias[co];
  for (int c = 0; c < 162; c++)
    #pragma unroll
    for (int k = 0; k < 3; k++)
      acc += w[(co*162 + c)*3 + k] * s[k][c];
  a3[(b*486 + co)*TAUX + q] = acc;
}

// ---------------- G[l][b][q][oc] = sum_c inx_w[l][oc][c] * a3[b][c][q] -----
__global__ void g_kernel(const float* a3, const float* inx_w, float* G) {
  __shared__ float s[486][15];
  int q0 = blockIdx.x * 15, b = blockIdx.y, l = blockIdx.z;
  int tid = threadIdx.x;
  for (int i = tid; i < 486*15; i += 384) {
    int c = i / 15, qq = i % 15;
    s[c][qq] = a3[(b*486 + c)*TAUX + q0 + qq];
  }
  __syncthreads();
  int oc = tid;
  float acc[15];
  #pragma unroll
  for (int qq = 0; qq < 15; qq++) acc[qq] = 0.f;
  const float* wrow = inx_w + (l*384 + oc)*486;
  for (int c = 0; c < 486; c++) {
    float w = wrow[c];
    #pragma unroll
    for (int qq = 0; qq < 15; qq++) acc[qq] += w * s[c][qq];
  }
  for (int qq = 0; qq < 15; qq++)
    G[((size_t)(l*NB + b)*TAUX + q0 + qq)*384 + oc] = acc[qq];
}

// ---------------- causal conv (256ch K=6) + softsign -> h0 -> slab0 --------
__global__ __launch_bounds__(256, 2)
void causal_kernel(const float* audio, const unsigned short* pk, const float* cb,
                   unsigned short* hbf)
{
  __shared__ __align__(16) unsigned short sA[72*264];   // [t_win][ic pad264]
  int b = blockIdx.y, t0 = blockIdx.x*64, tid = threadIdx.x;
  int wv = tid >> 6, lane = tid & 63, lanelo = lane & 15, lanehi = lane >> 4;

  for (int i = tid; i < 72*256; i += 256) {   // stage audio tile, bf16
    int ic = i / 72, tt = i % 72;
    int t = t0 - 5 + tt;
    float v = (t >= 0 && t < TLEN) ? audio[(size_t)(b*NQ + ic)*TLEN + t] : 0.f;
    sA[tt*264 + ic] = f2bf(v);
  }
  __syncthreads();

  f32x4 acc[4][3];
  f32x4 z4 = {0.f, 0.f, 0.f, 0.f};
  #pragma unroll
  for (int m = 0; m < 4; m++)
    #pragma unroll
    for (int i = 0; i < 3; i++) acc[m][i] = z4;

  for (int tap = 0; tap < 6; tap++) {
    for (int kc = 0; kc < 8; kc++) {
      bf16x8v A[4];
      int ko = kc*32 + (lanehi << 3);
      #pragma unroll
      for (int m = 0; m < 4; m++)
        A[m] = *(const bf16x8v*)&sA[(m*16 + lanelo + tap)*264 + ko];
      #pragma unroll
      for (int i = 0; i < 3; i++) {
        int nf = wv*3 + i;
        bf16x8v Bf = *(const bf16x8v*)&pk[(size_t)((((tap*8) + kc)*12 + nf)*64 + lane)*8];
        #pragma unroll
        for (int m = 0; m < 4; m++) acc[m][i] = mfma16(A[m], Bf, acc[m][i]);
      }
    }
  }

  unsigned short hv[4][3][4];
  #pragma unroll
  for (int m = 0; m < 4; m++)
    #pragma unroll
    for (int i = 0; i < 3; i++) {
      int oc = (wv*3 + i)*16 + lanelo;
      float bias = cb[oc];
      #pragma unroll
      for (int r = 0; r < 4; r++) {
        float v = acc[m][i][r] + bias;
        hv[m][i][r] = f2bf(v / (1.f + fabsf(v)));
      }
    }
  __syncthreads();
  #pragma unroll
  for (int m = 0; m < 4; m++)
    #pragma unroll
    for (int i = 0; i < 3; i++) {
      int oc = (wv*3 + i)*16 + lanelo;
      int cbh = oc >> 3, jh = oc & 7;
      #pragma unroll
      for (int r = 0; r < 4; r++) {
        int tl = m*16 + (lanehi << 2) + r;
        sA[tl*192 + ((cbh ^ (tl&7))<<3) + jh] = hv[m][i][r];
      }
    }
  __syncthreads();
  #pragma unroll
  for (int j = 0; j < 6; j++) {
    int c = tid + j*256, row = c/24, cbk = c%24;
    uint4 v = *(const uint4*)&sA[row*192 + ((cbk ^ (row&7))<<3)];
    *(uint4*)&hbf[(size_t)(b*HROWS + t0 + row + PADR)*HID + cbk*8] = v;
  }
}

// ---------------- persistent: 9 layers + skip-acc + out1/out2 --------------
// 208 blocks (52 tiles x 4 batch), 512 thr (2M x 4N waves), M=160/block.
// Own h chunk resident in LDS rows [180..339]; halo staged into [180-5d..179].
// h published to ping-pong slabs for neighbor halos; skip acc in registers.
__global__ __launch_bounds__(512)
void wavenet_kernel(const unsigned short* __restrict__ pk_dilh,
                    const float* __restrict__ dilh_b,
                    const unsigned short* __restrict__ pk_skip,
                    const float* __restrict__ skip_b,
                    const unsigned short* __restrict__ pk1, const float* __restrict__ b1,
                    const unsigned short* __restrict__ pk2, const float* __restrict__ b2,
                    const float* __restrict__ Gbuf, const float* __restrict__ Cbuf,
                    const float* __restrict__ up_w,
                    unsigned short* __restrict__ slab0,
                    unsigned short* __restrict__ slab1,
                    float* __restrict__ dout, unsigned int* cnt)
{
  extern __shared__ __align__(16) unsigned short hwin[];   // 340*192 shorts
  int id = blockIdx.x;
  int b = id / NTILES_P, tile = id % NTILES_P;
  int t0 = tile * 160;
  int tid = threadIdx.x;
  int wv = tid >> 6, lane = tid & 63, lanelo = lane & 15, lanehi = lane >> 4;
  int mwv = wv >> 2, nwv = wv & 3;
  const size_t hb = (size_t)b * HROWS * HID;
  f32x4 z4 = {0.f, 0.f, 0.f, 0.f};

  // load own 160 rows of h0 from slab0 into LDS rows 180..339
  for (int c = tid; c < 160*24; c += 512) {
    int row = c/24, cbk = c%24, lr = 180 + row;
    uint4 v = *(const uint4*)&slab0[hb + (size_t)(t0 + PADR + row)*HID + cbk*8];
    *(uint4*)&hwin[lr*192 + ((cbk ^ (lr&7))<<3)] = v;
  }

  f32x4 sacc[5][4];                       // skip accumulator, persists 9 layers
  #pragma unroll
  for (int m = 0; m < 5; m++)
    #pragma unroll
    for (int i = 0; i < 4; i++) sacc[m][i] = z4;

  for (int l = 0; l < 9; l++) {
    int lm3 = l - (l/3)*3;
    int dil = (lm3 == 0) ? 1 : ((lm3 == 1) ? 6 : 36);
    int H = 5*dil;
    const unsigned short* pkd = pk_dilh + (size_t)l*6*6*24*64*8;
    const float* db = dilh_b + l*384;
    const float* Gl = Gbuf + ((size_t)l*NB + b)*TAUX*384;
    const float* Cl = Cbuf + l*384;
    unsigned short* cur = (l & 1) ? slab1 : slab0;
    unsigned short* nxt = (l & 1) ? slab0 : slab1;

    // stage halo rows [t0-H, t0) from cur slab into LDS rows [180-H..179]
    for (int c = tid; c < H*24; c += 512) {
      int row = c/24, cbk = c%24, lr = 180 - H + row;
      uint4 v = *(const uint4*)&cur[hb + (size_t)(t0 + PADR - H + row)*HID + cbk*8];
      *(uint4*)&hwin[lr*192 + ((cbk ^ (lr&7))<<3)] = v;
    }
    __syncthreads();

    // dilated conv: 1080 MFMAs/wave
    f32x4 accz[5][3], acct[5][3];
    #pragma unroll
    for (int m = 0; m < 5; m++)
      #pragma unroll
      for (int i = 0; i < 3; i++) { accz[m][i] = z4; acct[m][i] = z4; }
    for (int tap = 0; tap < 6; tap++) {
      #pragma unroll
      for (int kc = 0; kc < 6; kc++) {
        bf16x8v A[5];
        int cbk = kc*4 + lanehi;
        #pragma unroll
        for (int m = 0; m < 5; m++) {
          int r = 180 - H + mwv*80 + m*16 + lanelo + tap*dil;
          A[m] = *(const bf16x8v*)&hwin[r*192 + ((cbk ^ (r&7))<<3)];
        }
        #pragma unroll
        for (int i = 0; i < 3; i++) {
          const unsigned short* bp =
              &pkd[(size_t)(((tap*6 + kc)*24 + nwv*3 + i)*64 + lane)*8];
          bf16x8v Bz = *(const bf16x8v*)bp;
          bf16x8v Bt = *(const bf16x8v*)(bp + 12*512);
          #pragma unroll
          for (int m = 0; m < 5; m++) {
            accz[m][i] = mfma16(A[m], Bz, accz[m][i]);
            acct[m][i] = mfma16(A[m], Bt, acct[m][i]);
          }
        }
      }
    }
    __syncthreads();   // all conv window reads complete

    // gate: in-place h update (each thread RMWs only its own [row][slice])
    float izc[3], itc[3], bzc[3], btc[3];
    #pragma unroll
    for (int i = 0; i < 3; i++) {
      int ocz = (nwv*3 + i)*16 + lanelo;
      izc[i] = Cl[ocz];  itc[i] = Cl[192 + ocz];
      bzc[i] = db[ocz];  btc[i] = db[192 + ocz];
    }
    #pragma unroll
    for (int m = 0; m < 5; m++) {
      #pragma unroll
      for (int r = 0; r < 4; r++) {
        int tl = mwv*80 + m*16 + (lanehi << 2) + r;
        int t = t0 + tl, lr = 180 + tl;
        int tp1 = t + 1;
        int q = tp1 / UPF; if (q > TAUX - 1) q = TAUX - 1;
        int ui = tp1 - q*UPF; if (ui > UPF - 1) ui = UPF - 1;
        float u = up_w[ui];
        const float* Gb = Gl + (size_t)q*384;
        #pragma unroll
        for (int i = 0; i < 3; i++) {
          int ocz = (nwv*3 + i)*16 + lanelo;
          float iz = u*Gb[ocz]       + izc[i];
          float it = u*Gb[192 + ocz] + itc[i];
          float xz = (accz[m][i][r] + bzc[i]) * iz;
          float xt = (acct[m][i][r] + btc[i]) * it;
          float z  = 1.f / (1.f + __expf(-xz));
          float e2 = __expf(2.f*xt);
          float th = 1.f - 2.f/(e2 + 1.f);
          int idx = lr*192 + (((ocz >> 3) ^ (lr&7)) << 3) + (ocz & 7);
          float hold = __uint_as_float(((unsigned int)hwin[idx]) << 16);
          hwin[idx] = f2bf((1.f - z)*th + z*hold);
        }
      }
    }
    __syncthreads();   // h_{l+1} tile complete in LDS

    // publish own rows for neighbors' next-layer halo (not needed after l=8)
    if (l < 8) {
      for (int c = tid; c < 160*24; c += 512) {
        int row = c/24, cbk = c%24, lr = 180 + row;
        uint4 v = *(const uint4*)&hwin[lr*192 + ((cbk ^ (lr&7))<<3)];
        *(uint4*)&nxt[hb + (size_t)(t0 + PADR + row)*HID + cbk*8] = v;
      }
    }

    // skip GEMM on h_{l+1} (LDS-resident), accumulate in registers
    const unsigned short* pks = pk_skip + (size_t)l*6*16*64*8;
    #pragma unroll
    for (int kc = 0; kc < 6; kc++) {
      bf16x8v A[5];
      int cbk = kc*4 + lanehi;
      #pragma unroll
      for (int m = 0; m < 5; m++) {
        int r = 180 + mwv*80 + m*16 + lanelo;
        A[m] = *(const bf16x8v*)&hwin[r*192 + ((cbk ^ (r&7))<<3)];
      }
      #pragma unroll
      for (int i = 0; i < 4; i++) {
        bf16x8v Bf = *(const bf16x8v*)&pks[(size_t)((kc*16 + nwv*4 + i)*64 + lane)*8];
        #pragma unroll
        for (int m = 0; m < 5; m++) sacc[m][i] = mfma16(A[m], Bf, sacc[m][i]);
      }
    }

    if (l < 8) gridbar(cnt, (unsigned)NBLK*(l+1), tid);
  }
  __syncthreads();   // done with hwin as h window

  // s tile = relu(sacc + sum_l skip_b[l]) -> LDS [160][264] bf16
  #pragma unroll
  for (int i = 0; i < 4; i++) {
    int sc = (nwv*4 + i)*16 + lanelo;
    float bias = 0.f;
    #pragma unroll
    for (int l = 0; l < 9; l++) bias += skip_b[l*NSKIP + sc];
    #pragma unroll
    for (int m = 0; m < 5; m++) {
      #pragma unroll
      for (int r = 0; r < 4; r++) {
        int tl = mwv*80 + m*16 + (lanehi << 2) + r;
        float v = sacc[m][i][r] + bias;
        hwin[tl*264 + sc] = f2bf(fmaxf(v, 0.f));
      }
    }
  }
  __syncthreads();

  // out1
  f32x4 oacc[5][4];
  #pragma unroll
  for (int m = 0; m < 5; m++)
    #pragma unroll
    for (int i = 0; i < 4; i++) oacc[m][i] = z4;
  for (int kc = 0; kc < 8; kc++) {
    bf16x8v A[5];
    int ko = kc*32 + (lanehi << 3);
    #pragma unroll
    for (int m = 0; m < 5; m++)
      A[m] = *(const bf16x8v*)&hwin[(mwv*80 + m*16 + lanelo)*264 + ko];
    #pragma unroll
    for (int i = 0; i < 4; i++) {
      bf16x8v Bf = *(const bf16x8v*)&pk1[(size_t)((kc*16 + nwv*4 + i)*64 + lane)*8];
      #pragma unroll
      for (int m = 0; m < 5; m++) oacc[m][i] = mfma16(A[m], Bf, oacc[m][i]);
    }
  }
  __syncthreads();
  #pragma unroll
  for (int m = 0; m < 5; m++)
    #pragma unroll
    for (int i = 0; i < 4; i++) {
      int oq = (nwv*4 + i)*16 + lanelo;
      float bias = b1[oq];
      #pragma unroll
      for (int r = 0; r < 4; r++) {
        int tl = mwv*80 + m*16 + (lanehi << 2) + r;
        hwin[tl*264 + oq] = f2bf(fmaxf(oacc[m][i][r] + bias, 0.f));
      }
    }
  __syncthreads();

  // out2
  #pragma unroll
  for (int m = 0; m < 5; m++)
    #pragma unroll
    for (int i = 0; i < 4; i++) oacc[m][i] = z4;
  for (int kc = 0; kc < 8; kc++) {
    bf16x8v A[5];
    int ko = kc*32 + (lanehi << 3);
    #pragma unroll
    for (int m = 0; m < 5; m++)
      A[m] = *(const bf16x8v*)&hwin[(mwv*80 + m*16 + lanelo)*264 + ko];
    #pragma unroll
    for (int i = 0; i < 4; i++) {
      bf16x8v Bf = *(const bf16x8v*)&pk2[(size_t)((kc*16 + nwv*4 + i)*64 + lane)*8];
      #pragma unroll
      for (int m = 0; m < 5; m++) oacc[m][i] = mfma16(A[m], Bf, oacc[m][i]);
    }
  }
  // two fp32 80-row stages, coalesced dout writes
  float* so2 = (float*)hwin;
  #pragma unroll
  for (int p = 0; p < 2; p++) {
    __syncthreads();
    if (mwv == p) {
      #pragma unroll
      for (int m = 0; m < 5; m++)
        #pragma unroll
        for (int i = 0; i < 4; i++) {
          int oq = (nwv*4 + i)*16 + lanelo;
          float bias = b2[oq];
          #pragma unroll
          for (int r = 0; r < 4; r++) {
            int lrr = m*16 + (lanehi << 2) + r;
            so2[lrr*260 + oq] = oacc[m][i][r] + bias;
          }
        }
    }
    __syncthreads();
    for (int c = tid; c < 80*64; c += 512) {
      int row = c >> 6, ch = c & 63;
      int t = t0 + p*80 + row;
      if (t < TLEN) {
        uint4 v = *(const uint4*)&so2[row*260 + ch*4];
        *(uint4*)&dout[(size_t)(b*TLEN + t)*NQ + ch*4] = v;
      }
    }
  }
}

// ---------------------------------------------------------------------------
extern "C" void kernel_launch(void* const* d_in, const int* in_sizes, int n_in,
                              void* d_out, int out_size, void* d_ws, size_t ws_size,
                              hipStream_t stream)
{
  const float* audio      = (const float*)d_in[0];
  const float* aux        = (const float*)d_in[1];
  const float* scale_in_w = (const float*)d_in[2];
  const float* scale_in_b = (const float*)d_in[3];
  const float* aux0_w     = (const float*)d_in[4];
  const float* aux0_b     = (const float*)d_in[5];
  const float* aux1_w     = (const float*)d_in[6];
  const float* aux1_b     = (const float*)d_in[7];
  const float* up_w       = (const float*)d_in[8];
  const float* up_b       = (const float*)d_in[9];
  const float* causal_w   = (const float*)d_in[10];
  const float* causal_b   = (const float*)d_in[11];
  const float* inx_w      = (const float*)d_in[12];
  const float* inx_b      = (const float*)d_in[13];
  const float* dilh_w     = (const float*)d_in[14];
  const float* dilh_b     = (const float*)d_in[15];
  const float* skip_w     = (const float*)d_in[16];
  const float* skip_b     = (const float*)d_in[17];
  const float* out1_w     = (const float*)d_in[18];
  const float* out1_b     = (const float*)d_in[19];
  const float* out2_w     = (const float*)d_in[20];
  const float* out2_b     = (const float*)d_in[21];

  char* ws = (char*)d_ws;
  size_t off = 0;
  auto alloc = [&](size_t bytes) -> void* {
    void* p = ws + off;
    off += (bytes + 255) & ~(size_t)255;
    return p;
  };
  unsigned short* pk_causal = (unsigned short*)alloc((size_t)6*8*12*64*8*2);
  unsigned short* pk_dilh   = (unsigned short*)alloc((size_t)9*6*6*24*64*8*2);
  unsigned short* pk_skip   = (unsigned short*)alloc((size_t)9*6*16*64*8*2);
  unsigned short* pk_out1   = (unsigned short*)alloc((size_t)8*16*64*8*2);
  unsigned short* pk_out2   = (unsigned short*)alloc((size_t)8*16*64*8*2);
  float* Cbuf    = (float*)alloc((size_t)9*384*4);
  float* a1      = (float*)alloc((size_t)NB*NAUX*TAUX*4);
  float* a2      = (float*)alloc((size_t)NB*162*TAUX*4);
  float* a3      = (float*)alloc((size_t)NB*486*TAUX*4);
  float* Gbuf    = (float*)alloc((size_t)9*NB*TAUX*384*4);
  const size_t HS = (size_t)NB*HROWS*HID;
  unsigned short* slab0 = (unsigned short*)alloc(HS*2);
  unsigned short* slab1 = (unsigned short*)alloc(HS*2);
  unsigned int* cnt = (unsigned int*)alloc(256);

  hipFuncSetAttribute((const void*)wavenet_kernel,
                      hipFuncAttributeMaxDynamicSharedMemorySize, 340*192*2);

  hipMemsetAsync(cnt, 0, 4, stream);
  hipLaunchKernelGGL(prepack_kernel, dim3((9*6*6*24*64*8 + 255)/256), dim3(256), 0, stream,
                     causal_w, dilh_w, skip_w, out1_w, out2_w, inx_w, inx_b, up_b,
                     pk_causal, pk_dilh, pk_skip, pk_out1, pk_out2, Cbuf);
  hipLaunchKernelGGL(zpad_kernel, dim3((NB*PADR*HID + 255)/256), dim3(256), 0, stream,
                     slab0, slab1);
  hipLaunchKernelGGL(aux1_kernel, dim3(TAUX, NB), dim3(64), 0, stream,
                     aux, scale_in_w, scale_in_b, a1);
  hipLaunchKernelGGL(aux2_kernel, dim3(TAUX, NB), dim3(192), 0, stream,
                     a1, aux0_w, aux0_b, a2);
  hipLaunchKernelGGL(aux3_kernel, dim3(TAUX, NB), dim3(512), 0, stream,
                     a2, aux1_w, aux1_b, a3);
  hipLaunchKernelGGL(g_kernel, dim3(5, NB, 9), dim3(384), 0, stream,
                     a3, inx_w, Gbuf);
  hipLaunchKernelGGL(causal_kernel, dim3(NTILES_C, NB), dim3(256), 0, stream,
                     audio, pk_causal, causal_b, slab0);

  hipLaunchKernelGGL(wavenet_kernel, dim3(NBLK), dim3(512), 340*192*2, stream,
                     pk_dilh, dilh_b, pk_skip, skip_b,
                     pk_out1, out1_b, pk_out2, out2_b,
                     Gbuf, Cbuf, up_w, slab0, slab1, (float*)d_out, cnt);
}

// Round 10
// 1191.134 us; speedup vs baseline: 1.0002x; 1.0002x over previous
//
#include <hip/hip_runtime.h>

#define TLEN 8249
#define TPAD 8320          // 65*128 == 130*64
#define NTILES 130
#define NTILES2 65
#define NB 4
#define NAUX 54
#define NQ 256
#define HID 192
#define NSKIP 256
#define KW 6
#define UPF 110
#define TAUX 75
#define PADR 180           // 5*36 max left reach of dilated conv
#define HROWS (PADR + TPAD)

typedef __attribute__((ext_vector_type(8))) short bf16x8v;
typedef __attribute__((ext_vector_type(4))) float f32x4;

__device__ __forceinline__ unsigned short f2bf(float f) {
  unsigned int u = __float_as_uint(f);
  u += 0x7FFFu + ((u >> 16) & 1u);   // RNE
  return (unsigned short)(u >> 16);
}

__device__ __forceinline__ f32x4 mfma16(bf16x8v a, bf16x8v b, f32x4 c) {
  return __builtin_amdgcn_mfma_f32_16x16x32_bf16(a, b, c, 0, 0, 0);
}

// ---------------- weight prepack (MFMA fragment order) + C vector ----------
__global__ void prepack_kernel(
    const float* causal_w, const float* dilh_w, const float* skip_w,
    const float* out1_w, const float* out2_w,
    const float* inx_w, const float* inx_b, const float* up_b,
    unsigned short* pk_causal, unsigned short* pk_dilh, unsigned short* pk_skip,
    unsigned short* pk_out1, unsigned short* pk_out2, float* Cbuf)
{
  int i = blockIdx.x * blockDim.x + threadIdx.x;
  if (i < 9*6*6*24*64*8) {            // dilh: [l][tap][kc6][nf24][lane][8]
    int t = i;
    int j = t & 7; t >>= 3;
    int lane = t & 63; t >>= 6;
    int nf = t % 24; t /= 24;
    int kc = t % 6; t /= 6;
    int tap = t % 6; t /= 6;
    int l = t;
    int oc = nf*16 + (lane & 15);
    int ic = kc*32 + ((lane >> 4) << 3) + j;
    pk_dilh[i] = f2bf(dilh_w[((l*384 + oc)*HID + ic)*KW + tap]);
  }
  if (i < 6*8*12*64*8) {              // causal: [tap][kc8][nf12][lane][8]
    int t = i;
    int j = t & 7; t >>= 3;
    int lane = t & 63; t >>= 6;
    int nf = t % 12; t /= 12;
    int kc = t % 8; t /= 8;
    int tap = t;
    int oc = nf*16 + (lane & 15);
    int ic = kc*32 + ((lane >> 4) << 3) + j;
    pk_causal[i] = f2bf(causal_w[(oc*NQ + ic)*KW + tap]);
  }
  if (i < 9*6*16*64*8) {              // skip: [l][kc6][nf16][lane][8]
    int t = i;
    int j = t & 7; t >>= 3;
    int lane = t & 63; t >>= 6;
    int nf = t % 16; t /= 16;
    int kc = t % 6; t /= 6;
    int l = t;
    int sc = nf*16 + (lane & 15);
    int ic = kc*32 + ((lane >> 4) << 3) + j;
    pk_skip[i] = f2bf(skip_w[(l*NSKIP + sc)*HID + ic]);
  }
  if (i < 8*16*64*8) {                // out1/out2: [kc8][nf16][lane][8]
    int t = i;
    int j = t & 7; t >>= 3;
    int lane = t & 63; t >>= 6;
    int nf = t % 16; t /= 16;
    int kc = t;
    int oq = nf*16 + (lane & 15);
    int sc = kc*32 + ((lane >> 4) << 3) + j;
    pk_out1[i] = f2bf(out1_w[oq*NSKIP + sc]);
    pk_out2[i] = f2bf(out2_w[oq*NQ + sc]);
  }
  if (i < 9*384) {                    // C[l][oc] = up_b*rowsum(inx_w)+inx_b
    int l = i / 384, oc = i % 384;
    const float* wr = inx_w + (l*384 + oc)*486;
    float s = 0.f;
    for (int c = 0; c < 486; c++) s += wr[c];
    Cbuf[i] = up_b[0]*s + inx_b[i];
  }
}

// ---------------- zero the 180-row causal pads of all 9 h slabs ------------
__global__ void zpad_kernel(unsigned short* h_all) {
  int i = blockIdx.x*blockDim.x + threadIdx.x;
  if (i < 9*NB*PADR*HID) {
    int slab = i / (NB*PADR*HID), r = i % (NB*PADR*HID);
    int b = r / (PADR*HID), rr = r % (PADR*HID);
    h_all[((size_t)slab*NB + b)*HROWS*HID + rr] = 0;
  }
}

// ---------------- tiny aux chain (all fp32) --------------------------------
__global__ void aux1_kernel(const float* aux, const float* w, const float* bias, float* a1) {
  int q = blockIdx.x, b = blockIdx.y, co = threadIdx.x;
  if (co >= NAUX) return;
  float acc = bias[co];
  for (int ci = 0; ci < NAUX; ci++)
    acc += w[co*NAUX + ci] * aux[(b*NAUX + ci)*TAUX + q];
  a1[(b*NAUX + co)*TAUX + q] = acc;
}

__global__ void aux2_kernel(const float* a1, const float* w, const float* bias, float* a2) {
  __shared__ float s[3][NAUX];
  int q = blockIdx.x, b = blockIdx.y, tid = threadIdx.x;
  for (int i = tid; i < 3*NAUX; i += blockDim.x) {
    int k = i / NAUX, c = i % NAUX;
    int qq = q - 1 + k;
    s[k][c] = (qq >= 0 && qq < TAUX) ? a1[(b*NAUX + c)*TAUX + qq] : 0.f;
  }
  __syncthreads();
  int co = tid;
  if (co >= 162) return;
  float acc = bias[co];
  for (int c = 0; c < NAUX; c++)
    #pragma unroll
    for (int k = 0; k < 3; k++)
      acc += w[(co*NAUX + c)*3 + k] * s[k][c];
  a2[(b*162 + co)*TAUX + q] = acc;
}

__global__ void aux3_kernel(const float* a2, const float* w, const float* bias, float* a3) {
  __shared__ float s[3][162];
  int q = blockIdx.x, b = blockIdx.y, tid = threadIdx.x;
  for (int i = tid; i < 3*162; i += blockDim.x) {
    int k = i / 162, c = i % 162;
    int qq = q + 3*(k - 1);
    s[k][c] = (qq >= 0 && qq < TAUX) ? a2[(b*162 + c)*TAUX + qq] : 0.f;
  }
  __syncthreads();
  int co = tid;
  if (co >= 486) return;
  float acc = bias[co];
  for (int c = 0; c < 162; c++)
    #pragma unroll
    for (int k = 0; k < 3; k++)
      acc += w[(co*162 + c)*3 + k] * s[k][c];
  a3[(b*486 + co)*TAUX + q] = acc;
}

// ---------------- G[l][b][q][oc] = sum_c inx_w[l][oc][c] * a3[b][c][q] -----
__global__ void g_kernel(const float* a3, const float* inx_w, float* G) {
  __shared__ float s[486][15];
  int q0 = blockIdx.x * 15, b = blockIdx.y, l = blockIdx.z;
  int tid = threadIdx.x;
  for (int i = tid; i < 486*15; i += 384) {
    int c = i / 15, qq = i % 15;
    s[c][qq] = a3[(b*486 + c)*TAUX + q0 + qq];
  }
  __syncthreads();
  int oc = tid;
  float acc[15];
  #pragma unroll
  for (int qq = 0; qq < 15; qq++) acc[qq] = 0.f;
  const float* wrow = inx_w + (l*384 + oc)*486;
  for (int c = 0; c < 486; c++) {
    float w = wrow[c];
    #pragma unroll
    for (int qq = 0; qq < 15; qq++) acc[qq] += w * s[c][qq];
  }
  for (int qq = 0; qq < 15; qq++)
    G[((size_t)(l*NB + b)*TAUX + q0 + qq)*384 + oc] = acc[qq];
}

// ---------------- causal conv (256ch K=6) + softsign -> h0 (bf16) ----------
__global__ __launch_bounds__(256, 2)
void causal_kernel(const float* audio, const unsigned short* pk, const float* cb,
                   unsigned short* hbf)
{
  __shared__ __align__(16) unsigned short sA[72*264];   // [t_win][ic pad264]
  int b = blockIdx.y, t0 = blockIdx.x*64, tid = threadIdx.x;
  int wv = tid >> 6, lane = tid & 63, lanelo = lane & 15, lanehi = lane >> 4;

  for (int i = tid; i < 72*256; i += 256) {   // stage audio tile, bf16
    int ic = i / 72, tt = i % 72;
    int t = t0 - 5 + tt;
    float v = (t >= 0 && t < TLEN) ? audio[(size_t)(b*NQ + ic)*TLEN + t] : 0.f;
    sA[tt*264 + ic] = f2bf(v);
  }
  __syncthreads();

  f32x4 acc[4][3];
  f32x4 z4 = {0.f, 0.f, 0.f, 0.f};
  #pragma unroll
  for (int m = 0; m < 4; m++)
    #pragma unroll
    for (int i = 0; i < 3; i++) acc[m][i] = z4;

  for (int tap = 0; tap < 6; tap++) {
    for (int kc = 0; kc < 8; kc++) {
      bf16x8v A[4];
      int ko = kc*32 + (lanehi << 3);
      #pragma unroll
      for (int m = 0; m < 4; m++)
        A[m] = *(const bf16x8v*)&sA[(m*16 + lanelo + tap)*264 + ko];
      #pragma unroll
      for (int i = 0; i < 3; i++) {
        int nf = wv*3 + i;
        bf16x8v Bf = *(const bf16x8v*)&pk[(size_t)((((tap*8) + kc)*12 + nf)*64 + lane)*8];
        #pragma unroll
        for (int m = 0; m < 4; m++) acc[m][i] = mfma16(A[m], Bf, acc[m][i]);
      }
    }
  }

  unsigned short hv[4][3][4];
  #pragma unroll
  for (int m = 0; m < 4; m++)
    #pragma unroll
    for (int i = 0; i < 3; i++) {
      int oc = (wv*3 + i)*16 + lanelo;
      float bias = cb[oc];
      #pragma unroll
      for (int r = 0; r < 4; r++) {
        float v = acc[m][i][r] + bias;
        hv[m][i][r] = f2bf(v / (1.f + fabsf(v)));
      }
    }
  __syncthreads();
  #pragma unroll
  for (int m = 0; m < 4; m++)
    #pragma unroll
    for (int i = 0; i < 3; i++) {
      int oc = (wv*3 + i)*16 + lanelo;
      int cbh = oc >> 3, jh = oc & 7;
      #pragma unroll
      for (int r = 0; r < 4; r++) {
        int tl = m*16 + (lanehi << 2) + r;
        sA[tl*192 + ((cbh ^ (tl&7))<<3) + jh] = hv[m][i][r];
      }
    }
  __syncthreads();
  #pragma unroll
  for (int j = 0; j < 6; j++) {
    int c = tid + j*256, row = c/24, cbk = c%24;
    uint4 v = *(const uint4*)&sA[row*192 + ((cbk ^ (row&7))<<3)];
    *(uint4*)&hbf[(size_t)(b*HROWS + t0 + row + PADR)*HID + cbk*8] = v;
  }
}

// ---------------- layer (dil 1/6): M=128, 512 thr, union window ------------
// 2M x 4N wave groups; W<=158 rows LDS (60.7KB) -> 2 blocks/CU, 260 blocks.
__global__ __launch_bounds__(512, 2)
void layer_u_kernel(int dil,
                    const unsigned short* __restrict__ hin,
                    unsigned short* __restrict__ hout,
                    const unsigned short* __restrict__ pk_dilh_l,
                    const float* __restrict__ dilh_b_l,
                    const float* __restrict__ Gl, const float* __restrict__ Cl,
                    const float* __restrict__ up_w)
{
  __shared__ __align__(16) unsigned short flat[158*192];   // 60672 B
  int b = blockIdx.y, t0 = blockIdx.x*128, tid = threadIdx.x;
  int wv = tid >> 6, lane = tid & 63, lanelo = lane & 15, lanehi = lane >> 4;
  int mwv = wv >> 2, nwv = wv & 3;

  const size_t hbase = (size_t)b * HROWS * HID;
  int rowbase0 = t0 - 5*dil + PADR;            // >= 0 always
  int W = 128 + 5*dil;                         // 133 or 158

  for (int c = tid; c < W*24; c += 512) {
    int row = c/24, cbk = c%24;
    uint4 v = *(const uint4*)&hin[hbase + (size_t)(rowbase0+row)*HID + cbk*8];
    *(uint4*)&flat[row*192 + ((cbk ^ (row&7))<<3)] = v;
  }
  __syncthreads();

  f32x4 accz[4][3], acct[4][3];
  f32x4 z4 = {0.f, 0.f, 0.f, 0.f};
  #pragma unroll
  for (int m = 0; m < 4; m++)
    #pragma unroll
    for (int i = 0; i < 3; i++) { accz[m][i] = z4; acct[m][i] = z4; }

  for (int tap = 0; tap < 6; tap++) {
    #pragma unroll
    for (int kc = 0; kc < 6; kc++) {
      bf16x8v A[4];
      int cbk = kc*4 + lanehi;
      #pragma unroll
      for (int m = 0; m < 4; m++) {
        int r = mwv*64 + m*16 + lanelo + tap*dil;
        A[m] = *(const bf16x8v*)&flat[r*192 + ((cbk ^ (r&7))<<3)];
      }
      #pragma unroll
      for (int i = 0; i < 3; i++) {
        const unsigned short* bp =
            &pk_dilh_l[(size_t)(((tap*6 + kc)*24 + nwv*3 + i)*64 + lane)*8];
        bf16x8v Bz = *(const bf16x8v*)bp;
        bf16x8v Bt = *(const bf16x8v*)(bp + 12*512);
        #pragma unroll
        for (int m = 0; m < 4; m++) {
          accz[m][i] = mfma16(A[m], Bz, accz[m][i]);
          acct[m][i] = mfma16(A[m], Bt, acct[m][i]);
        }
      }
    }
  }

  // gate into registers (h_old at window row tl+5*dil)
  float izc[3], itc[3], bzc[3], btc[3];
  #pragma unroll
  for (int i = 0; i < 3; i++) {
    int ocz = (nwv*3 + i)*16 + lanelo;
    izc[i] = Cl[ocz];       itc[i] = Cl[192 + ocz];
    bzc[i] = dilh_b_l[ocz]; btc[i] = dilh_b_l[192 + ocz];
  }
  unsigned short hnv[4][4][3];
  #pragma unroll
  for (int m = 0; m < 4; m++) {
    #pragma unroll
    for (int r = 0; r < 4; r++) {
      int tl = mwv*64 + m*16 + (lanehi << 2) + r;
      int t = t0 + tl;
      int hr = tl + 5*dil;
      int tp1 = t + 1;
      int q = tp1 / UPF; if (q > TAUX - 1) q = TAUX - 1;
      int ui = tp1 - q*UPF; if (ui > UPF - 1) ui = UPF - 1;
      float u = up_w[ui];
      const float* Gb = Gl + (size_t)(b*TAUX + q)*384;
      #pragma unroll
      for (int i = 0; i < 3; i++) {
        int ocz = (nwv*3 + i)*16 + lanelo;
        float iz = u*Gb[ocz]       + izc[i];
        float it = u*Gb[192 + ocz] + itc[i];
        float xz = (accz[m][i][r] + bzc[i]) * iz;
        float xt = (acct[m][i][r] + btc[i]) * it;
        float z  = 1.f / (1.f + __expf(-xz));
        float e2 = __expf(2.f*xt);
        float th = 1.f - 2.f/(e2 + 1.f);
        int cbh = ocz >> 3, jh = ocz & 7;
        unsigned short hob = flat[hr*192 + ((cbh ^ (hr&7))<<3) + jh];
        float hold = __uint_as_float(((unsigned int)hob) << 16);
        hnv[m][r][i] = f2bf((1.f - z)*th + z*hold);
      }
    }
  }
  __syncthreads();
  #pragma unroll
  for (int m = 0; m < 4; m++) {
    #pragma unroll
    for (int r = 0; r < 4; r++) {
      int tl = mwv*64 + m*16 + (lanehi << 2) + r;
      #pragma unroll
      for (int i = 0; i < 3; i++) {
        int ocz = (nwv*3 + i)*16 + lanelo;
        int cbh = ocz >> 3, jh = ocz & 7;
        flat[tl*192 + ((cbh ^ (tl&7))<<3) + jh] = hnv[m][r][i];
      }
    }
  }
  __syncthreads();
  #pragma unroll
  for (int j = 0; j < 6; j++) {
    int c = tid + j*512, row = c/24, cbk = c%24;
    uint4 v = *(const uint4*)&flat[row*192 + ((cbk ^ (row&7))<<3)];
    *(uint4*)&hout[hbase + (size_t)(t0 + row + PADR)*HID + cbk*8] = v;
  }
}

// ---------------- layer (dil 36): M=64, 256 thr, per-tap dbuf strips -------
__global__ __launch_bounds__(256, 3)
void layer_d_kernel(const unsigned short* __restrict__ hin,
                    unsigned short* __restrict__ hout,
                    const unsigned short* __restrict__ pk_dilh_l,
                    const float* __restrict__ dilh_b_l,
                    const float* __restrict__ Gl, const float* __restrict__ Cl,
                    const float* __restrict__ up_w)
{
  __shared__ __align__(16) unsigned short hs[2][64*192];   // 49152 B
  int b = blockIdx.y, t0 = blockIdx.x*64, tid = threadIdx.x;
  int wv = tid >> 6, lane = tid & 63, lanelo = lane & 15, lanehi = lane >> 4;

  const size_t hbase = (size_t)b * HROWS * HID;
  int rowbase0 = t0 - 180 + PADR;

  f32x4 accz[4][3], acct[4][3];
  f32x4 z4 = {0.f, 0.f, 0.f, 0.f};
  #pragma unroll
  for (int m = 0; m < 4; m++)
    #pragma unroll
    for (int i = 0; i < 3; i++) { accz[m][i] = z4; acct[m][i] = z4; }

  uint4 st[6];
  #pragma unroll
  for (int j = 0; j < 6; j++) {
    int c = tid + j*256, row = c/24, cbk = c%24;
    st[j] = *(const uint4*)&hin[hbase + (size_t)(rowbase0+row)*HID + cbk*8];
  }
  #pragma unroll
  for (int j = 0; j < 6; j++) {
    int c = tid + j*256, row = c/24, cbk = c%24;
    *(uint4*)&hs[0][row*192 + ((cbk ^ (row&7))<<3)] = st[j];
  }
  for (int tap = 0; tap < 6; tap++) {
    __syncthreads();
    if (tap < 5) {
      int rb = rowbase0 + (tap+1)*36;
      #pragma unroll
      for (int j = 0; j < 6; j++) {
        int c = tid + j*256, row = c/24, cbk = c%24;
        st[j] = *(const uint4*)&hin[hbase + (size_t)(rb+row)*HID + cbk*8];
      }
    }
    const unsigned short* bufc = hs[tap & 1];
    #pragma unroll
    for (int kc = 0; kc < 6; kc++) {
      bf16x8v A[4];
      #pragma unroll
      for (int m = 0; m < 4; m++) {
        int r = m*16 + lanelo;
        int cbk = kc*4 + lanehi;
        A[m] = *(const bf16x8v*)&bufc[r*192 + ((cbk ^ (r&7))<<3)];
      }
      #pragma unroll
      for (int i = 0; i < 3; i++) {
        const unsigned short* bp =
            &pk_dilh_l[(size_t)(((tap*6 + kc)*24 + wv*3 + i)*64 + lane)*8];
        bf16x8v Bz = *(const bf16x8v*)bp;
        bf16x8v Bt = *(const bf16x8v*)(bp + 12*512);
        #pragma unroll
        for (int m = 0; m < 4; m++) {
          accz[m][i] = mfma16(A[m], Bz, accz[m][i]);
          acct[m][i] = mfma16(A[m], Bt, acct[m][i]);
        }
      }
    }
    if (tap < 5) {
      unsigned short* bufn = hs[(tap+1) & 1];
      #pragma unroll
      for (int j = 0; j < 6; j++) {
        int c = tid + j*256, row = c/24, cbk = c%24;
        *(uint4*)&bufn[row*192 + ((cbk ^ (row&7))<<3)] = st[j];
      }
    }
  }

  // gate (h_old = tap5 strip = hs[1] rows tl)
  float izc[3], itc[3], bzc[3], btc[3];
  #pragma unroll
  for (int i = 0; i < 3; i++) {
    int ocz = (wv*3 + i)*16 + lanelo;
    izc[i] = Cl[ocz];       itc[i] = Cl[192 + ocz];
    bzc[i] = dilh_b_l[ocz]; btc[i] = dilh_b_l[192 + ocz];
  }
  unsigned short hnv[4][4][3];
  #pragma unroll
  for (int m = 0; m < 4; m++) {
    #pragma unroll
    for (int r = 0; r < 4; r++) {
      int tl = m*16 + (lanehi << 2) + r;
      int t = t0 + tl;
      int tp1 = t + 1;
      int q = tp1 / UPF; if (q > TAUX - 1) q = TAUX - 1;
      int ui = tp1 - q*UPF; if (ui > UPF - 1) ui = UPF - 1;
      float u = up_w[ui];
      const float* Gb = Gl + (size_t)(b*TAUX + q)*384;
      #pragma unroll
      for (int i = 0; i < 3; i++) {
        int ocz = (wv*3 + i)*16 + lanelo;
        float iz = u*Gb[ocz]       + izc[i];
        float it = u*Gb[192 + ocz] + itc[i];
        float xz = (accz[m][i][r] + bzc[i]) * iz;
        float xt = (acct[m][i][r] + btc[i]) * it;
        float z  = 1.f / (1.f + __expf(-xz));
        float e2 = __expf(2.f*xt);
        float th = 1.f - 2.f/(e2 + 1.f);
        int cbh = ocz >> 3, jh = ocz & 7;
        unsigned short hob = hs[1][tl*192 + ((cbh ^ (tl&7))<<3) + jh];
        float hold = __uint_as_float(((unsigned int)hob) << 16);
        hnv[m][r][i] = f2bf((1.f - z)*th + z*hold);
      }
    }
  }
  __syncthreads();
  unsigned short* flat = &hs[0][0];
  #pragma unroll
  for (int m = 0; m < 4; m++) {
    #pragma unroll
    for (int r = 0; r < 4; r++) {
      int tl = m*16 + (lanehi << 2) + r;
      #pragma unroll
      for (int i = 0; i < 3; i++) {
        int ocz = (wv*3 + i)*16 + lanelo;
        int cbh = ocz >> 3, jh = ocz & 7;
        flat[tl*192 + ((cbh ^ (tl&7))<<3) + jh] = hnv[m][r][i];
      }
    }
  }
  __syncthreads();
  #pragma unroll
  for (int j = 0; j < 6; j++) {
    int c = tid + j*256, row = c/24, cbk = c%24;
    uint4 v = *(const uint4*)&flat[row*192 + ((cbk ^ (row&7))<<3)];
    *(uint4*)&hout[hbase + (size_t)(t0 + row + PADR)*HID + cbk*8] = v;
  }
}

// ---------------- skipsum: M=128, 512 thr, single-buf + T14 ----------------
__global__ __launch_bounds__(512, 2)
void skipsum_kernel(const unsigned short* __restrict__ h_all,
                    const unsigned short* __restrict__ pk_skip,
                    const float* __restrict__ skip_b,
                    unsigned short* __restrict__ sbuf)
{
  __shared__ __align__(16) unsigned short ss[128*192];   // 49152 B
  int b = blockIdx.y, t0 = blockIdx.x*128, tid = threadIdx.x;
  int wv = tid >> 6, lane = tid & 63, lanelo = lane & 15, lanehi = lane >> 4;
  int mwv = wv >> 2, nwv = wv & 3;
  const size_t HS = (size_t)NB * HROWS * HID;

  auto hsrc = [&](int l) {
    int slab = (l == 8) ? 0 : (l + 1);
    return h_all + (size_t)slab*HS + (size_t)b*HROWS*HID + (size_t)(t0 + PADR)*HID;
  };

  uint4 st[6];
  {  // prologue: stage layer 0 (128 rows x 24 chunks)
    const unsigned short* src = hsrc(0);
    #pragma unroll
    for (int j = 0; j < 6; j++) {
      int c = tid + j*512, row = c/24, cbk = c%24;
      st[j] = *(const uint4*)&src[(size_t)row*HID + cbk*8];
    }
    #pragma unroll
    for (int j = 0; j < 6; j++) {
      int c = tid + j*512, row = c/24, cbk = c%24;
      *(uint4*)&ss[row*192 + ((cbk ^ (row&7))<<3)] = st[j];
    }
  }

  f32x4 acc[4][4];
  f32x4 z4 = {0.f, 0.f, 0.f, 0.f};
  #pragma unroll
  for (int m = 0; m < 4; m++)
    #pragma unroll
    for (int i = 0; i < 4; i++) acc[m][i] = z4;

  for (int l = 0; l < 9; l++) {
    if (l < 8) {           // T14: issue next-layer loads before the barrier
      const unsigned short* src = hsrc(l + 1);
      #pragma unroll
      for (int j = 0; j < 6; j++) {
        int c = tid + j*512, row = c/24, cbk = c%24;
        st[j] = *(const uint4*)&src[(size_t)row*HID + cbk*8];
      }
    }
    __syncthreads();       // ss holds layer l
    #pragma unroll
    for (int kc = 0; kc < 6; kc++) {
      bf16x8v A[4];
      #pragma unroll
      for (int m = 0; m < 4; m++) {
        int r = mwv*64 + m*16 + lanelo;
        int cbk = kc*4 + lanehi;
        A[m] = *(const bf16x8v*)&ss[r*192 + ((cbk ^ (r&7))<<3)];
      }
      #pragma unroll
      for (int i = 0; i < 4; i++) {
        bf16x8v Bf = *(const bf16x8v*)
            &pk_skip[(size_t)(((l*6 + kc)*16 + nwv*4 + i)*64 + lane)*8];
        #pragma unroll
        for (int m = 0; m < 4; m++) acc[m][i] = mfma16(A[m], Bf, acc[m][i]);
      }
    }
    __syncthreads();       // reads of ss done
    if (l < 8) {
      #pragma unroll
      for (int j = 0; j < 6; j++) {
        int c = tid + j*512, row = c/24, cbk = c%24;
        *(uint4*)&ss[row*192 + ((cbk ^ (row&7))<<3)] = st[j];
      }
    }
  }

  // epilogue: two 64-row halves via [64][264] tile, coalesced copy-out
  float biasv[4];
  #pragma unroll
  for (int i = 0; i < 4; i++) {
    int sc = (nwv*4 + i)*16 + lanelo;
    float bias = 0.f;
    #pragma unroll
    for (int l = 0; l < 9; l++) bias += skip_b[l*NSKIP + sc];
    biasv[i] = bias;
  }
  #pragma unroll
  for (int p = 0; p < 2; p++) {
    if (mwv == p) {
      #pragma unroll
      for (int i = 0; i < 4; i++) {
        int sc = (nwv*4 + i)*16 + lanelo;
        #pragma unroll
        for (int m = 0; m < 4; m++) {
          #pragma unroll
          for (int r = 0; r < 4; r++) {
            int lr = m*16 + (lanehi << 2) + r;
            ss[lr*264 + sc] = f2bf(fmaxf(acc[m][i][r] + biasv[i], 0.f));
          }
        }
      }
    }
    __syncthreads();
    #pragma unroll
    for (int j = 0; j < 4; j++) {
      int c = tid + j*512, row = c >> 5, cbk = c & 31;
      uint4 v = *(const uint4*)&ss[row*264 + cbk*8];
      *(uint4*)&sbuf[(size_t)(b*TPAD + t0 + p*64 + row)*NSKIP + cbk*8] = v;
    }
    __syncthreads();
  }
}

// ---------------- out = out2(relu(out1(s))), write (b,t,q) fp32 ------------
__global__ __launch_bounds__(256, 2)
void out_kernel(const unsigned short* sbuf, const unsigned short* pk1, const float* b1,
                const unsigned short* pk2, const float* b2, float* dout)
{
  __shared__ __align__(16) unsigned short s0[64*264];
  __shared__ __align__(16) float so2[32*260];
  int b = blockIdx.y, t0 = blockIdx.x*64, tid = threadIdx.x;
  int wv = tid >> 6, lane = tid & 63, lanelo = lane & 15, lanehi = lane >> 4;
  f32x4 z4 = {0.f, 0.f, 0.f, 0.f};

  for (int i = tid; i < 64*32; i += 256) {     // stage s tile (already relu'd)
    int r = i >> 5, cbk = i & 31;
    *(uint4*)&s0[r*264 + cbk*8] =
        *(const uint4*)&sbuf[(size_t)(b*TPAD + t0 + r)*NSKIP + cbk*8];
  }
  __syncthreads();

  f32x4 acc[4][4];
  #pragma unroll
  for (int m = 0; m < 4; m++)
    #pragma unroll
    for (int i = 0; i < 4; i++) acc[m][i] = z4;
  for (int kc = 0; kc < 8; kc++) {
    bf16x8v A[4];
    int ko = kc*32 + (lanehi << 3);
    #pragma unroll
    for (int m = 0; m < 4; m++)
      A[m] = *(const bf16x8v*)&s0[(m*16 + lanelo)*264 + ko];
    #pragma unroll
    for (int i = 0; i < 4; i++) {
      int nf = wv*4 + i;
      bf16x8v Bf = *(const bf16x8v*)&pk1[(size_t)((kc*16 + nf)*64 + lane)*8];
      #pragma unroll
      for (int m = 0; m < 4; m++) acc[m][i] = mfma16(A[m], Bf, acc[m][i]);
    }
  }
  __syncthreads();
  #pragma unroll
  for (int m = 0; m < 4; m++)
    #pragma unroll
    for (int i = 0; i < 4; i++) {
      int oq = (wv*4 + i)*16 + lanelo;
      float bias = b1[oq];
      #pragma unroll
      for (int r = 0; r < 4; r++) {
        int tl = m*16 + (lanehi << 2) + r;
        float v = acc[m][i][r] + bias;
        s0[tl*264 + oq] = f2bf(fmaxf(v, 0.f));
      }
    }
  __syncthreads();

  #pragma unroll
  for (int m = 0; m < 4; m++)
    #pragma unroll
    for (int i = 0; i < 4; i++) acc[m][i] = z4;
  for (int kc = 0; kc < 8; kc++) {
    bf16x8v A[4];
    int ko = kc*32 + (lanehi << 3);
    #pragma unroll
    for (int m = 0; m < 4; m++)
      A[m] = *(const bf16x8v*)&s0[(m*16 + lanelo)*264 + ko];
    #pragma unroll
    for (int i = 0; i < 4; i++) {
      int nf = wv*4 + i;
      bf16x8v Bf = *(const bf16x8v*)&pk2[(size_t)((kc*16 + nf)*64 + lane)*8];
      #pragma unroll
      for (int m = 0; m < 4; m++) acc[m][i] = mfma16(A[m], Bf, acc[m][i]);
    }
  }
  #pragma unroll
  for (int p = 0; p < 2; p++) {
    __syncthreads();
    #pragma unroll
    for (int mm = 0; mm < 2; mm++) {
      int m = p*2 + mm;
      #pragma unroll
      for (int i = 0; i < 4; i++) {
        int oq = (wv*4 + i)*16 + lanelo;
        float bias = b2[oq];
        #pragma unroll
        for (int r = 0; r < 4; r++) {
          int lr = mm*16 + (lanehi << 2) + r;
          so2[lr*260 + oq] = acc[m][i][r] + bias;
        }
      }
    }
    __syncthreads();
    #pragma unroll
    for (int j = 0; j < 8; j++) {
      int c = tid + j*256, row = c >> 6, ch = c & 63;
      int t = t0 + p*32 + row;
      if (t < TLEN) {
        uint4 v = *(const uint4*)&so2[row*260 + ch*4];
        *(uint4*)&dout[(size_t)(b*TLEN + t)*NQ + ch*4] = v;
      }
    }
  }
}

// ---------------------------------------------------------------------------
extern "C" void kernel_launch(void* const* d_in, const int* in_sizes, int n_in,
                              void* d_out, int out_size, void* d_ws, size_t ws_size,
                              hipStream_t stream)
{
  const float* audio      = (const float*)d_in[0];
  const float* aux        = (const float*)d_in[1];
  const float* scale_in_w = (const float*)d_in[2];
  const float* scale_in_b = (const float*)d_in[3];
  const float* aux0_w     = (const float*)d_in[4];
  const float* aux0_b     = (const float*)d_in[5];
  const float* aux1_w     = (const float*)d_in[6];
  const float* aux1_b     = (const float*)d_in[7];
  const float* up_w       = (const float*)d_in[8];
  const float* up_b       = (const float*)d_in[9];
  const float* causal_w   = (const float*)d_in[10];
  const float* causal_b   = (const float*)d_in[11];
  const float* inx_w      = (const float*)d_in[12];
  const float* inx_b      = (const float*)d_in[13];
  const float* dilh_w     = (const float*)d_in[14];
  const float* dilh_b     = (const float*)d_in[15];
  const float* skip_w     = (const float*)d_in[16];
  const float* skip_b     = (const float*)d_in[17];
  const float* out1_w     = (const float*)d_in[18];
  const float* out1_b     = (const float*)d_in[19];
  const float* out2_w     = (const float*)d_in[20];
  const float* out2_b     = (const float*)d_in[21];

  char* ws = (char*)d_ws;
  size_t off = 0;
  auto alloc = [&](size_t bytes) -> void* {
    void* p = ws + off;
    off += (bytes + 255) & ~(size_t)255;
    return p;
  };
  unsigned short* pk_causal = (unsigned short*)alloc((size_t)6*8*12*64*8*2);
  unsigned short* pk_dilh   = (unsigned short*)alloc((size_t)9*6*6*24*64*8*2);
  unsigned short* pk_skip   = (unsigned short*)alloc((size_t)9*6*16*64*8*2);
  unsigned short* pk_out1   = (unsigned short*)alloc((size_t)8*16*64*8*2);
  unsigned short* pk_out2   = (unsigned short*)alloc((size_t)8*16*64*8*2);
  float* Cbuf    = (float*)alloc((size_t)9*384*4);
  float* a1      = (float*)alloc((size_t)NB*NAUX*TAUX*4);
  float* a2      = (float*)alloc((size_t)NB*162*TAUX*4);
  float* a3      = (float*)alloc((size_t)NB*486*TAUX*4);
  float* Gbuf    = (float*)alloc((size_t)9*NB*TAUX*384*4);
  const size_t HS = (size_t)NB*HROWS*HID;
  unsigned short* h_all = (unsigned short*)alloc((size_t)9*HS*2);  // slabs 0..8
  unsigned short* sbuf  = (unsigned short*)alloc((size_t)NB*TPAD*NSKIP*2);

  hipLaunchKernelGGL(prepack_kernel, dim3((9*6*6*24*64*8 + 255)/256), dim3(256), 0, stream,
                     causal_w, dilh_w, skip_w, out1_w, out2_w, inx_w, inx_b, up_b,
                     pk_causal, pk_dilh, pk_skip, pk_out1, pk_out2, Cbuf);
  hipLaunchKernelGGL(zpad_kernel, dim3((9*NB*PADR*HID + 255)/256), dim3(256), 0, stream,
                     h_all);
  hipLaunchKernelGGL(aux1_kernel, dim3(TAUX, NB), dim3(64), 0, stream,
                     aux, scale_in_w, scale_in_b, a1);
  hipLaunchKernelGGL(aux2_kernel, dim3(TAUX, NB), dim3(192), 0, stream,
                     a1, aux0_w, aux0_b, a2);
  hipLaunchKernelGGL(aux3_kernel, dim3(TAUX, NB), dim3(512), 0, stream,
                     a2, aux1_w, aux1_b, a3);
  hipLaunchKernelGGL(g_kernel, dim3(5, NB, 9), dim3(384), 0, stream,
                     a3, inx_w, Gbuf);
  hipLaunchKernelGGL(causal_kernel, dim3(NTILES, NB), dim3(256), 0, stream,
                     audio, pk_causal, causal_b, h_all /* slab 0 = h_0 */);

  const int dils[9] = {1, 6, 36, 1, 6, 36, 1, 6, 36};
  for (int l = 0; l < 9; l++) {
    const unsigned short* hin = h_all + (size_t)l*HS;
    unsigned short* hout      = (l == 8) ? h_all : h_all + (size_t)(l+1)*HS;
    if (dils[l] == 36) {
      hipLaunchKernelGGL(layer_d_kernel, dim3(NTILES, NB), dim3(256), 0, stream,
                         hin, hout,
                         pk_dilh + (size_t)l*6*6*24*64*8,
                         dilh_b + (size_t)l*384,
                         Gbuf + (size_t)l*NB*TAUX*384,
                         Cbuf + (size_t)l*384,
                         up_w);
    } else {
      hipLaunchKernelGGL(layer_u_kernel, dim3(NTILES2, NB), dim3(512), 0, stream,
                         dils[l], hin, hout,
                         pk_dilh + (size_t)l*6*6*24*64*8,
                         dilh_b + (size_t)l*384,
                         Gbuf + (size_t)l*NB*TAUX*384,
                         Cbuf + (size_t)l*384,
                         up_w);
    }
  }

  hipLaunchKernelGGL(skipsum_kernel, dim3(NTILES2, NB), dim3(512), 0, stream,
                     h_all, pk_skip, skip_b, sbuf);
  hipLaunchKernelGGL(out_kernel, dim3(NTILES, NB), dim3(256), 0, stream,
                     sbuf, pk_out1, out1_b, pk_out2, out2_b, (float*)d_out);
}

// Round 11
// 1141.602 us; speedup vs baseline: 1.0436x; 1.0434x over previous
//
#include <hip/hip_runtime.h>

#define TLEN 8249
#define TPAD 8320          // 130*64
#define NTILES 130
#define NBLK 520           // 130*4, == 8*65 (XCD-bijective)
#define NB 4
#define NAUX 54
#define NQ 256
#define HID 192
#define NSKIP 256
#define KW 6
#define UPF 110
#define TAUX 75
#define PADR 180           // 5*36 max left reach of dilated conv
#define HROWS (PADR + TPAD)

typedef __attribute__((ext_vector_type(8))) short bf16x8v;
typedef __attribute__((ext_vector_type(4))) float f32x4;

__device__ __forceinline__ unsigned short f2bf(float f) {
  unsigned int u = __float_as_uint(f);
  u += 0x7FFFu + ((u >> 16) & 1u);   // RNE
  return (unsigned short)(u >> 16);
}

__device__ __forceinline__ f32x4 mfma16(bf16x8v a, bf16x8v b, f32x4 c) {
  return __builtin_amdgcn_mfma_f32_16x16x32_bf16(a, b, c, 0, 0, 0);
}

// XCD-bijective block swizzle: 520 blocks = 8 XCDs x 65 contiguous work items.
// Same mapping in every tiled kernel -> a tile's h stays in the same XCD's L2
// across layers (producer/consumer locality), halo neighbors contiguous.
__device__ __forceinline__ int swz520(int bid) {
  return (bid & 7) * 65 + (bid >> 3);
}

// ---------------- weight prepack (MFMA fragment order) + C vector ----------
__global__ void prepack_kernel(
    const float* causal_w, const float* dilh_w, const float* skip_w,
    const float* out1_w, const float* out2_w,
    const float* inx_w, const float* inx_b, const float* up_b,
    unsigned short* pk_causal, unsigned short* pk_dilh, unsigned short* pk_skip,
    unsigned short* pk_out1, unsigned short* pk_out2, float* Cbuf)
{
  int i = blockIdx.x * blockDim.x + threadIdx.x;
  if (i < 9*6*6*24*64*8) {            // dilh: [l][tap][kc6][nf24][lane][8]
    int t = i;
    int j = t & 7; t >>= 3;
    int lane = t & 63; t >>= 6;
    int nf = t % 24; t /= 24;
    int kc = t % 6; t /= 6;
    int tap = t % 6; t /= 6;
    int l = t;
    int oc = nf*16 + (lane & 15);
    int ic = kc*32 + ((lane >> 4) << 3) + j;
    pk_dilh[i] = f2bf(dilh_w[((l*384 + oc)*HID + ic)*KW + tap]);
  }
  if (i < 6*8*12*64*8) {              // causal: [tap][kc8][nf12][lane][8]
    int t = i;
    int j = t & 7; t >>= 3;
    int lane = t & 63; t >>= 6;
    int nf = t % 12; t /= 12;
    int kc = t % 8; t /= 8;
    int tap = t;
    int oc = nf*16 + (lane & 15);
    int ic = kc*32 + ((lane >> 4) << 3) + j;
    pk_causal[i] = f2bf(causal_w[(oc*NQ + ic)*KW + tap]);
  }
  if (i < 9*6*16*64*8) {              // skip: [l][kc6][nf16][lane][8]
    int t = i;
    int j = t & 7; t >>= 3;
    int lane = t & 63; t >>= 6;
    int nf = t % 16; t /= 16;
    int kc = t % 6; t /= 6;
    int l = t;
    int sc = nf*16 + (lane & 15);
    int ic = kc*32 + ((lane >> 4) << 3) + j;
    pk_skip[i] = f2bf(skip_w[(l*NSKIP + sc)*HID + ic]);
  }
  if (i < 8*16*64*8) {                // out1/out2: [kc8][nf16][lane][8]
    int t = i;
    int j = t & 7; t >>= 3;
    int lane = t & 63; t >>= 6;
    int nf = t % 16; t /= 16;
    int kc = t;
    int oq = nf*16 + (lane & 15);
    int sc = kc*32 + ((lane >> 4) << 3) + j;
    pk_out1[i] = f2bf(out1_w[oq*NSKIP + sc]);
    pk_out2[i] = f2bf(out2_w[oq*NQ + sc]);
  }
  if (i < 9*384) {                    // C[l][oc] = up_b*rowsum(inx_w)+inx_b
    int l = i / 384, oc = i % 384;
    const float* wr = inx_w + (l*384 + oc)*486;
    float s = 0.f;
    for (int c = 0; c < 486; c++) s += wr[c];
    Cbuf[i] = up_b[0]*s + inx_b[i];
  }
}

// ---------------- zero the 180-row causal pads of all 9 h slabs ------------
__global__ void zpad_kernel(unsigned short* h_all) {
  int i = blockIdx.x*blockDim.x + threadIdx.x;
  if (i < 9*NB*PADR*HID) {
    int slab = i / (NB*PADR*HID), r = i % (NB*PADR*HID);
    int b = r / (PADR*HID), rr = r % (PADR*HID);
    h_all[((size_t)slab*NB + b)*HROWS*HID + rr] = 0;
  }
}

// ---------------- tiny aux chain (all fp32) --------------------------------
__global__ void aux1_kernel(const float* aux, const float* w, const float* bias, float* a1) {
  int q = blockIdx.x, b = blockIdx.y, co = threadIdx.x;
  if (co >= NAUX) return;
  float acc = bias[co];
  for (int ci = 0; ci < NAUX; ci++)
    acc += w[co*NAUX + ci] * aux[(b*NAUX + ci)*TAUX + q];
  a1[(b*NAUX + co)*TAUX + q] = acc;
}

__global__ void aux2_kernel(const float* a1, const float* w, const float* bias, float* a2) {
  __shared__ float s[3][NAUX];
  int q = blockIdx.x, b = blockIdx.y, tid = threadIdx.x;
  for (int i = tid; i < 3*NAUX; i += blockDim.x) {
    int k = i / NAUX, c = i % NAUX;
    int qq = q - 1 + k;
    s[k][c] = (qq >= 0 && qq < TAUX) ? a1[(b*NAUX + c)*TAUX + qq] : 0.f;
  }
  __syncthreads();
  int co = tid;
  if (co >= 162) return;
  float acc = bias[co];
  for (int c = 0; c < NAUX; c++)
    #pragma unroll
    for (int k = 0; k < 3; k++)
      acc += w[(co*NAUX + c)*3 + k] * s[k][c];
  a2[(b*162 + co)*TAUX + q] = acc;
}

__global__ void aux3_kernel(const float* a2, const float* w, const float* bias, float* a3) {
  __shared__ float s[3][162];
  int q = blockIdx.x, b = blockIdx.y, tid = threadIdx.x;
  for (int i = tid; i < 3*162; i += blockDim.x) {
    int k = i / 162, c = i % 162;
    int qq = q + 3*(k - 1);
    s[k][c] = (qq >= 0 && qq < TAUX) ? a2[(b*162 + c)*TAUX + qq] : 0.f;
  }
  __syncthreads();
  int co = tid;
  if (co >= 486) return;
  float acc = bias[co];
  for (int c = 0; c < 162; c++)
    #pragma unroll
    for (int k = 0; k < 3; k++)
      acc += w[(co*162 + c)*3 + k] * s[k][c];
  a3[(b*486 + co)*TAUX + q] = acc;
}

// ---------------- G[l][b][q][oc] = sum_c inx_w[l][oc][c] * a3[b][c][q] -----
__global__ void g_kernel(const float* a3, const float* inx_w, float* G) {
  __shared__ float s[486][15];
  int q0 = blockIdx.x * 15, b = blockIdx.y, l = blockIdx.z;
  int tid = threadIdx.x;
  for (int i = tid; i < 486*15; i += 384) {
    int c = i / 15, qq = i % 15;
    s[c][qq] = a3[(b*486 + c)*TAUX + q0 + qq];
  }
  __syncthreads();
  int oc = tid;
  float acc[15];
  #pragma unroll
  for (int qq = 0; qq < 15; qq++) acc[qq] = 0.f;
  const float* wrow = inx_w + (l*384 + oc)*486;
  for (int c = 0; c < 486; c++) {
    float w = wrow[c];
    #pragma unroll
    for (int qq = 0; qq < 15; qq++) acc[qq] += w * s[c][qq];
  }
  for (int qq = 0; qq < 15; qq++)
    G[((size_t)(l*NB + b)*TAUX + q0 + qq)*384 + oc] = acc[qq];
}

// ---------------- causal conv (256ch K=6) + softsign -> h0 (bf16) ----------
__global__ __launch_bounds__(256, 3)
void causal_kernel(const float* audio, const unsigned short* pk, const float* cb,
                   unsigned short* hbf)
{
  __shared__ __align__(16) unsigned short sA[72*264];   // [t_win][ic pad264]
  int wg = swz520(blockIdx.x);
  int b = wg / NTILES, t0 = (wg % NTILES)*64, tid = threadIdx.x;
  int wv = tid >> 6, lane = tid & 63, lanelo = lane & 15, lanehi = lane >> 4;

  for (int i = tid; i < 72*256; i += 256) {   // stage audio tile, bf16
    int ic = i / 72, tt = i % 72;
    int t = t0 - 5 + tt;
    float v = (t >= 0 && t < TLEN) ? audio[(size_t)(b*NQ + ic)*TLEN + t] : 0.f;
    sA[tt*264 + ic] = f2bf(v);
  }
  __syncthreads();

  f32x4 acc[4][3];
  f32x4 z4 = {0.f, 0.f, 0.f, 0.f};
  #pragma unroll
  for (int m = 0; m < 4; m++)
    #pragma unroll
    for (int i = 0; i < 3; i++) acc[m][i] = z4;

  for (int tap = 0; tap < 6; tap++) {
    for (int kc = 0; kc < 8; kc++) {
      bf16x8v A[4];
      int ko = kc*32 + (lanehi << 3);
      #pragma unroll
      for (int m = 0; m < 4; m++)
        A[m] = *(const bf16x8v*)&sA[(m*16 + lanelo + tap)*264 + ko];
      #pragma unroll
      for (int i = 0; i < 3; i++) {
        int nf = wv*3 + i;
        bf16x8v Bf = *(const bf16x8v*)&pk[(size_t)((((tap*8) + kc)*12 + nf)*64 + lane)*8];
        #pragma unroll
        for (int m = 0; m < 4; m++) acc[m][i] = mfma16(A[m], Bf, acc[m][i]);
      }
    }
  }

  unsigned short hv[4][3][4];
  #pragma unroll
  for (int m = 0; m < 4; m++)
    #pragma unroll
    for (int i = 0; i < 3; i++) {
      int oc = (wv*3 + i)*16 + lanelo;
      float bias = cb[oc];
      #pragma unroll
      for (int r = 0; r < 4; r++) {
        float v = acc[m][i][r] + bias;
        hv[m][i][r] = f2bf(v / (1.f + fabsf(v)));
      }
    }
  __syncthreads();
  #pragma unroll
  for (int m = 0; m < 4; m++)
    #pragma unroll
    for (int i = 0; i < 3; i++) {
      int oc = (wv*3 + i)*16 + lanelo;
      int cbh = oc >> 3, jh = oc & 7;
      #pragma unroll
      for (int r = 0; r < 4; r++) {
        int tl = m*16 + (lanehi << 2) + r;
        sA[tl*192 + ((cbh ^ (tl&7))<<3) + jh] = hv[m][i][r];
      }
    }
  __syncthreads();
  #pragma unroll
  for (int j = 0; j < 6; j++) {
    int c = tid + j*256, row = c/24, cbk = c%24;
    uint4 v = *(const uint4*)&sA[row*192 + ((cbk ^ (row&7))<<3)];
    *(uint4*)&hbf[(size_t)(b*HROWS + t0 + row + PADR)*HID + cbk*8] = v;
  }
}

// ---------------- layer (dil 1/6): M=64, 256 thr, union window, 4 blk/CU ---
__global__ __launch_bounds__(256, 4)
void layer_u_kernel(int dil,
                    const unsigned short* __restrict__ hin,
                    unsigned short* __restrict__ hout,
                    const unsigned short* __restrict__ pk_dilh_l,
                    const float* __restrict__ dilh_b_l,
                    const float* __restrict__ Gl, const float* __restrict__ Cl,
                    const float* __restrict__ up_w)
{
  __shared__ __align__(16) unsigned short flat[94*192];   // 36096 B -> 4 blk/CU
  int wg = swz520(blockIdx.x);
  int b = wg / NTILES, t0 = (wg % NTILES)*64, tid = threadIdx.x;
  int wv = tid >> 6, lane = tid & 63, lanelo = lane & 15, lanehi = lane >> 4;

  const size_t hbase = (size_t)b * HROWS * HID;
  int rowbase0 = t0 - 5*dil + PADR;            // >= 0 always
  int W = 64 + 5*dil;                          // 69 or 94

  for (int c = tid; c < W*24; c += 256) {
    int row = c/24, cbk = c%24;
    uint4 v = *(const uint4*)&hin[hbase + (size_t)(rowbase0+row)*HID + cbk*8];
    *(uint4*)&flat[row*192 + ((cbk ^ (row&7))<<3)] = v;
  }
  __syncthreads();

  f32x4 accz[4][3], acct[4][3];
  f32x4 z4 = {0.f, 0.f, 0.f, 0.f};
  #pragma unroll
  for (int m = 0; m < 4; m++)
    #pragma unroll
    for (int i = 0; i < 3; i++) { accz[m][i] = z4; acct[m][i] = z4; }

  for (int tap = 0; tap < 6; tap++) {
    #pragma unroll
    for (int kc = 0; kc < 6; kc++) {
      bf16x8v A[4];
      int cbk = kc*4 + lanehi;
      #pragma unroll
      for (int m = 0; m < 4; m++) {
        int r = m*16 + lanelo + tap*dil;
        A[m] = *(const bf16x8v*)&flat[r*192 + ((cbk ^ (r&7))<<3)];
      }
      #pragma unroll
      for (int i = 0; i < 3; i++) {
        const unsigned short* bp =
            &pk_dilh_l[(size_t)(((tap*6 + kc)*24 + wv*3 + i)*64 + lane)*8];
        bf16x8v Bz = *(const bf16x8v*)bp;
        bf16x8v Bt = *(const bf16x8v*)(bp + 12*512);
        #pragma unroll
        for (int m = 0; m < 4; m++) {
          accz[m][i] = mfma16(A[m], Bz, accz[m][i]);
          acct[m][i] = mfma16(A[m], Bt, acct[m][i]);
        }
      }
    }
  }

  // gate: h_new = (1-z)*tanh + z*h_old (h_old from LDS), scattered writes
  float izc[3], itc[3], bzc[3], btc[3];
  #pragma unroll
  for (int i = 0; i < 3; i++) {
    int ocz = (wv*3 + i)*16 + lanelo;
    izc[i] = Cl[ocz];       itc[i] = Cl[192 + ocz];
    bzc[i] = dilh_b_l[ocz]; btc[i] = dilh_b_l[192 + ocz];
  }
  #pragma unroll
  for (int m = 0; m < 4; m++) {
    #pragma unroll
    for (int r = 0; r < 4; r++) {
      int tl = m*16 + (lanehi << 2) + r;
      int t = t0 + tl;
      int hr = tl + 5*dil;
      int tp1 = t + 1;
      int q = tp1 / UPF; if (q > TAUX - 1) q = TAUX - 1;
      int ui = tp1 - q*UPF; if (ui > UPF - 1) ui = UPF - 1;
      float u = up_w[ui];
      const float* Gb = Gl + (size_t)(b*TAUX + q)*384;
      #pragma unroll
      for (int i = 0; i < 3; i++) {
        int ocz = (wv*3 + i)*16 + lanelo;
        float iz = u*Gb[ocz]       + izc[i];
        float it = u*Gb[192 + ocz] + itc[i];
        float xz = (accz[m][i][r] + bzc[i]) * iz;
        float xt = (acct[m][i][r] + btc[i]) * it;
        float z  = 1.f / (1.f + __expf(-xz));
        float e2 = __expf(2.f*xt);
        float th = 1.f - 2.f/(e2 + 1.f);
        int cbh = ocz >> 3, jh = ocz & 7;
        unsigned short hob = flat[hr*192 + ((cbh ^ (hr&7))<<3) + jh];
        float hold = __uint_as_float(((unsigned int)hob) << 16);
        float hn = (1.f - z)*th + z*hold;
        hout[hbase + (size_t)(t + PADR)*HID + ocz] = f2bf(hn);
      }
    }
  }
}

// ---------------- layer (dil 36): M=64, 256 thr, per-tap dbuf, 3 blk/CU ----
__global__ __launch_bounds__(256, 3)
void layer_d_kernel(const unsigned short* __restrict__ hin,
                    unsigned short* __restrict__ hout,
                    const unsigned short* __restrict__ pk_dilh_l,
                    const float* __restrict__ dilh_b_l,
                    const float* __restrict__ Gl, const float* __restrict__ Cl,
                    const float* __restrict__ up_w)
{
  __shared__ __align__(16) unsigned short hs[2][64*192];   // 49152 B
  int wg = swz520(blockIdx.x);
  int b = wg / NTILES, t0 = (wg % NTILES)*64, tid = threadIdx.x;
  int wv = tid >> 6, lane = tid & 63, lanelo = lane & 15, lanehi = lane >> 4;

  const size_t hbase = (size_t)b * HROWS * HID;
  int rowbase0 = t0 - 180 + PADR;

  f32x4 accz[4][3], acct[4][3];
  f32x4 z4 = {0.f, 0.f, 0.f, 0.f};
  #pragma unroll
  for (int m = 0; m < 4; m++)
    #pragma unroll
    for (int i = 0; i < 3; i++) { accz[m][i] = z4; acct[m][i] = z4; }

  uint4 st[6];
  #pragma unroll
  for (int j = 0; j < 6; j++) {
    int c = tid + j*256, row = c/24, cbk = c%24;
    st[j] = *(const uint4*)&hin[hbase + (size_t)(rowbase0+row)*HID + cbk*8];
  }
  #pragma unroll
  for (int j = 0; j < 6; j++) {
    int c = tid + j*256, row = c/24, cbk = c%24;
    *(uint4*)&hs[0][row*192 + ((cbk ^ (row&7))<<3)] = st[j];
  }
  for (int tap = 0; tap < 6; tap++) {
    __syncthreads();
    if (tap < 5) {
      int rb = rowbase0 + (tap+1)*36;
      #pragma unroll
      for (int j = 0; j < 6; j++) {
        int c = tid + j*256, row = c/24, cbk = c%24;
        st[j] = *(const uint4*)&hin[hbase + (size_t)(rb+row)*HID + cbk*8];
      }
    }
    const unsigned short* bufc = hs[tap & 1];
    #pragma unroll
    for (int kc = 0; kc < 6; kc++) {
      bf16x8v A[4];
      #pragma unroll
      for (int m = 0; m < 4; m++) {
        int r = m*16 + lanelo;
        int cbk = kc*4 + lanehi;
        A[m] = *(const bf16x8v*)&bufc[r*192 + ((cbk ^ (r&7))<<3)];
      }
      #pragma unroll
      for (int i = 0; i < 3; i++) {
        const unsigned short* bp =
            &pk_dilh_l[(size_t)(((tap*6 + kc)*24 + wv*3 + i)*64 + lane)*8];
        bf16x8v Bz = *(const bf16x8v*)bp;
        bf16x8v Bt = *(const bf16x8v*)(bp + 12*512);
        #pragma unroll
        for (int m = 0; m < 4; m++) {
          accz[m][i] = mfma16(A[m], Bz, accz[m][i]);
          acct[m][i] = mfma16(A[m], Bt, acct[m][i]);
        }
      }
    }
    if (tap < 5) {
      unsigned short* bufn = hs[(tap+1) & 1];
      #pragma unroll
      for (int j = 0; j < 6; j++) {
        int c = tid + j*256, row = c/24, cbk = c%24;
        *(uint4*)&bufn[row*192 + ((cbk ^ (row&7))<<3)] = st[j];
      }
    }
  }

  // gate (h_old = tap5 strip = hs[1] rows tl), scattered writes
  float izc[3], itc[3], bzc[3], btc[3];
  #pragma unroll
  for (int i = 0; i < 3; i++) {
    int ocz = (wv*3 + i)*16 + lanelo;
    izc[i] = Cl[ocz];       itc[i] = Cl[192 + ocz];
    bzc[i] = dilh_b_l[ocz]; btc[i] = dilh_b_l[192 + ocz];
  }
  #pragma unroll
  for (int m = 0; m < 4; m++) {
    #pragma unroll
    for (int r = 0; r < 4; r++) {
      int tl = m*16 + (lanehi << 2) + r;
      int t = t0 + tl;
      int tp1 = t + 1;
      int q = tp1 / UPF; if (q > TAUX - 1) q = TAUX - 1;
      int ui = tp1 - q*UPF; if (ui > UPF - 1) ui = UPF - 1;
      float u = up_w[ui];
      const float* Gb = Gl + (size_t)(b*TAUX + q)*384;
      #pragma unroll
      for (int i = 0; i < 3; i++) {
        int ocz = (wv*3 + i)*16 + lanelo;
        float iz = u*Gb[ocz]       + izc[i];
        float it = u*Gb[192 + ocz] + itc[i];
        float xz = (accz[m][i][r] + bzc[i]) * iz;
        float xt = (acct[m][i][r] + btc[i]) * it;
        float z  = 1.f / (1.f + __expf(-xz));
        float e2 = __expf(2.f*xt);
        float th = 1.f - 2.f/(e2 + 1.f);
        int cbh = ocz >> 3, jh = ocz & 7;
        unsigned short hob = hs[1][tl*192 + ((cbh ^ (tl&7))<<3) + jh];
        float hold = __uint_as_float(((unsigned int)hob) << 16);
        float hn = (1.f - z)*th + z*hold;
        hout[hbase + (size_t)(t + PADR)*HID + ocz] = f2bf(hn);
      }
    }
  }
}

// ---------------- skipsum: M=64, 256 thr, dbuf, 3 blk/CU (R7 config) -------
__global__ __launch_bounds__(256, 3)
void skipsum_kernel(const unsigned short* __restrict__ h_all,
                    const unsigned short* __restrict__ pk_skip,
                    const float* __restrict__ skip_b,
                    unsigned short* __restrict__ sbuf)
{
  __shared__ __align__(16) unsigned short ss[2][64*192];
  int wg = swz520(blockIdx.x);
  int b = wg / NTILES, t0 = (wg % NTILES)*64, tid = threadIdx.x;
  int wv = tid >> 6, lane = tid & 63, lanelo = lane & 15, lanehi = lane >> 4;
  const size_t HS = (size_t)NB * HROWS * HID;

  auto hsrc = [&](int l) {
    int slab = (l == 8) ? 0 : (l + 1);
    return h_all + (size_t)slab*HS + (size_t)b*HROWS*HID + (size_t)(t0 + PADR)*HID;
  };

  uint4 st[6];
  {
    const unsigned short* src = hsrc(0);
    #pragma unroll
    for (int j = 0; j < 6; j++) {
      int c = tid + j*256, row = c/24, cbk = c%24;
      st[j] = *(const uint4*)&src[(size_t)row*HID + cbk*8];
    }
    #pragma unroll
    for (int j = 0; j < 6; j++) {
      int c = tid + j*256, row = c/24, cbk = c%24;
      *(uint4*)&ss[0][row*192 + ((cbk ^ (row&7))<<3)] = st[j];
    }
  }

  f32x4 acc[4][4];
  f32x4 z4 = {0.f, 0.f, 0.f, 0.f};
  #pragma unroll
  for (int m = 0; m < 4; m++)
    #pragma unroll
    for (int i = 0; i < 4; i++) acc[m][i] = z4;

  for (int l = 0; l < 9; l++) {
    __syncthreads();
    if (l < 8) {
      const unsigned short* src = hsrc(l + 1);
      #pragma unroll
      for (int j = 0; j < 6; j++) {
        int c = tid + j*256, row = c/24, cbk = c%24;
        st[j] = *(const uint4*)&src[(size_t)row*HID + cbk*8];
      }
    }
    const unsigned short* bufc = ss[l & 1];
    #pragma unroll
    for (int kc = 0; kc < 6; kc++) {
      bf16x8v A[4];
      #pragma unroll
      for (int m = 0; m < 4; m++) {
        int r = m*16 + lanelo;
        int cbk = kc*4 + lanehi;
        A[m] = *(const bf16x8v*)&bufc[r*192 + ((cbk ^ (r&7))<<3)];
      }
      #pragma unroll
      for (int i = 0; i < 4; i++) {
        bf16x8v Bf = *(const bf16x8v*)
            &pk_skip[(size_t)(((l*6 + kc)*16 + wv*4 + i)*64 + lane)*8];
        #pragma unroll
        for (int m = 0; m < 4; m++) acc[m][i] = mfma16(A[m], Bf, acc[m][i]);
      }
    }
    if (l < 8) {
      unsigned short* bufn = ss[(l+1) & 1];
      #pragma unroll
      for (int j = 0; j < 6; j++) {
        int c = tid + j*256, row = c/24, cbk = c%24;
        *(uint4*)&bufn[row*192 + ((cbk ^ (row&7))<<3)] = st[j];
      }
    }
  }
  __syncthreads();   // all MFMA A-reads done; reuse ss as [64][256] tile

  unsigned short* tile = &ss[0][0];
  #pragma unroll
  for (int i = 0; i < 4; i++) {
    int sc = (wv*4 + i)*16 + lanelo;
    float bias = 0.f;
    #pragma unroll
    for (int l = 0; l < 9; l++) bias += skip_b[l*NSKIP + sc];
    int cbh = sc >> 3, jh = sc & 7;
    #pragma unroll
    for (int m = 0; m < 4; m++) {
      #pragma unroll
      for (int r = 0; r < 4; r++) {
        int tl = m*16 + (lanehi << 2) + r;
        float v = acc[m][i][r] + bias;
        tile[tl*256 + ((cbh ^ (tl&7))<<3) + jh] = f2bf(fmaxf(v, 0.f));
      }
    }
  }
  __syncthreads();
  #pragma unroll
  for (int j = 0; j < 8; j++) {
    int c = tid + j*256, row = c >> 5, cbk = c & 31;
    uint4 v = *(const uint4*)&tile[row*256 + ((cbk ^ (row&7))<<3)];
    *(uint4*)&sbuf[(size_t)(b*TPAD + t0 + row)*NSKIP + cbk*8] = v;
  }
}

// ---------------- out = out2(relu(out1(s))), write (b,t,q) fp32 ------------
__global__ __launch_bounds__(256, 2)
void out_kernel(const unsigned short* sbuf, const unsigned short* pk1, const float* b1,
                const unsigned short* pk2, const float* b2, float* dout)
{
  __shared__ __align__(16) unsigned short s0[64*264];
  __shared__ __align__(16) float so2[32*260];
  int wg = swz520(blockIdx.x);
  int b = wg / NTILES, t0 = (wg % NTILES)*64, tid = threadIdx.x;
  int wv = tid >> 6, lane = tid & 63, lanelo = lane & 15, lanehi = lane >> 4;
  f32x4 z4 = {0.f, 0.f, 0.f, 0.f};

  for (int i = tid; i < 64*32; i += 256) {     // stage s tile (already relu'd)
    int r = i >> 5, cbk = i & 31;
    *(uint4*)&s0[r*264 + cbk*8] =
        *(const uint4*)&sbuf[(size_t)(b*TPAD + t0 + r)*NSKIP + cbk*8];
  }
  __syncthreads();

  f32x4 acc[4][4];
  #pragma unroll
  for (int m = 0; m < 4; m++)
    #pragma unroll
    for (int i = 0; i < 4; i++) acc[m][i] = z4;
  for (int kc = 0; kc < 8; kc++) {
    bf16x8v A[4];
    int ko = kc*32 + (lanehi << 3);
    #pragma unroll
    for (int m = 0; m < 4; m++)
      A[m] = *(const bf16x8v*)&s0[(m*16 + lanelo)*264 + ko];
    #pragma unroll
    for (int i = 0; i < 4; i++) {
      int nf = wv*4 + i;
      bf16x8v Bf = *(const bf16x8v*)&pk1[(size_t)((kc*16 + nf)*64 + lane)*8];
      #pragma unroll
      for (int m = 0; m < 4; m++) acc[m][i] = mfma16(A[m], Bf, acc[m][i]);
    }
  }
  __syncthreads();
  #pragma unroll
  for (int m = 0; m < 4; m++)
    #pragma unroll
    for (int i = 0; i < 4; i++) {
      int oq = (wv*4 + i)*16 + lanelo;
      float bias = b1[oq];
      #pragma unroll
      for (int r = 0; r < 4; r++) {
        int tl = m*16 + (lanehi << 2) + r;
        float v = acc[m][i][r] + bias;
        s0[tl*264 + oq] = f2bf(fmaxf(v, 0.f));
      }
    }
  __syncthreads();

  #pragma unroll
  for (int m = 0; m < 4; m++)
    #pragma unroll
    for (int i = 0; i < 4; i++) acc[m][i] = z4;
  for (int kc = 0; kc < 8; kc++) {
    bf16x8v A[4];
    int ko = kc*32 + (lanehi << 3);
    #pragma unroll
    for (int m = 0; m < 4; m++)
      A[m] = *(const bf16x8v*)&s0[(m*16 + lanelo)*264 + ko];
    #pragma unroll
    for (int i = 0; i < 4; i++) {
      int nf = wv*4 + i;
      bf16x8v Bf = *(const bf16x8v*)&pk2[(size_t)((kc*16 + nf)*64 + lane)*8];
      #pragma unroll
      for (int m = 0; m < 4; m++) acc[m][i] = mfma16(A[m], Bf, acc[m][i]);
    }
  }
  #pragma unroll
  for (int p = 0; p < 2; p++) {
    __syncthreads();
    #pragma unroll
    for (int mm = 0; mm < 2; mm++) {
      int m = p*2 + mm;
      #pragma unroll
      for (int i = 0; i < 4; i++) {
        int oq = (wv*4 + i)*16 + lanelo;
        float bias = b2[oq];
        #pragma unroll
        for (int r = 0; r < 4; r++) {
          int lr = mm*16 + (lanehi << 2) + r;
          so2[lr*260 + oq] = acc[m][i][r] + bias;
        }
      }
    }
    __syncthreads();
    #pragma unroll
    for (int j = 0; j < 8; j++) {
      int c = tid + j*256, row = c >> 6, ch = c & 63;
      int t = t0 + p*32 + row;
      if (t < TLEN) {
        uint4 v = *(const uint4*)&so2[row*260 + ch*4];
        *(uint4*)&dout[(size_t)(b*TLEN + t)*NQ + ch*4] = v;
      }
    }
  }
}

// ---------------------------------------------------------------------------
extern "C" void kernel_launch(void* const* d_in, const int* in_sizes, int n_in,
                              void* d_out, int out_size, void* d_ws, size_t ws_size,
                              hipStream_t stream)
{
  const float* audio      = (const float*)d_in[0];
  const float* aux        = (const float*)d_in[1];
  const float* scale_in_w = (const float*)d_in[2];
  const float* scale_in_b = (const float*)d_in[3];
  const float* aux0_w     = (const float*)d_in[4];
  const float* aux0_b     = (const float*)d_in[5];
  const float* aux1_w     = (const float*)d_in[6];
  const float* aux1_b     = (const float*)d_in[7];
  const float* up_w       = (const float*)d_in[8];
  const float* up_b       = (const float*)d_in[9];
  const float* causal_w   = (const float*)d_in[10];
  const float* causal_b   = (const float*)d_in[11];
  const float* inx_w      = (const float*)d_in[12];
  const float* inx_b      = (const float*)d_in[13];
  const float* dilh_w     = (const float*)d_in[14];
  const float* dilh_b     = (const float*)d_in[15];
  const float* skip_w     = (const float*)d_in[16];
  const float* skip_b     = (const float*)d_in[17];
  const float* out1_w     = (const float*)d_in[18];
  const float* out1_b     = (const float*)d_in[19];
  const float* out2_w     = (const float*)d_in[20];
  const float* out2_b     = (const float*)d_in[21];

  char* ws = (char*)d_ws;
  size_t off = 0;
  auto alloc = [&](size_t bytes) -> void* {
    void* p = ws + off;
    off += (bytes + 255) & ~(size_t)255;
    return p;
  };
  unsigned short* pk_causal = (unsigned short*)alloc((size_t)6*8*12*64*8*2);
  unsigned short* pk_dilh   = (unsigned short*)alloc((size_t)9*6*6*24*64*8*2);
  unsigned short* pk_skip   = (unsigned short*)alloc((size_t)9*6*16*64*8*2);
  unsigned short* pk_out1   = (unsigned short*)alloc((size_t)8*16*64*8*2);
  unsigned short* pk_out2   = (unsigned short*)alloc((size_t)8*16*64*8*2);
  float* Cbuf    = (float*)alloc((size_t)9*384*4);
  float* a1      = (float*)alloc((size_t)NB*NAUX*TAUX*4);
  float* a2      = (float*)alloc((size_t)NB*162*TAUX*4);
  float* a3      = (float*)alloc((size_t)NB*486*TAUX*4);
  float* Gbuf    = (float*)alloc((size_t)9*NB*TAUX*384*4);
  const size_t HS = (size_t)NB*HROWS*HID;
  unsigned short* h_all = (unsigned short*)alloc((size_t)9*HS*2);  // slabs 0..8
  unsigned short* sbuf  = (unsigned short*)alloc((size_t)NB*TPAD*NSKIP*2);

  hipLaunchKernelGGL(prepack_kernel, dim3((9*6*6*24*64*8 + 255)/256), dim3(256), 0, stream,
                     causal_w, dilh_w, skip_w, out1_w, out2_w, inx_w, inx_b, up_b,
                     pk_causal, pk_dilh, pk_skip, pk_out1, pk_out2, Cbuf);
  hipLaunchKernelGGL(zpad_kernel, dim3((9*NB*PADR*HID + 255)/256), dim3(256), 0, stream,
                     h_all);
  hipLaunchKernelGGL(aux1_kernel, dim3(TAUX, NB), dim3(64), 0, stream,
                     aux, scale_in_w, scale_in_b, a1);
  hipLaunchKernelGGL(aux2_kernel, dim3(TAUX, NB), dim3(192), 0, stream,
                     a1, aux0_w, aux0_b, a2);
  hipLaunchKernelGGL(aux3_kernel, dim3(TAUX, NB), dim3(512), 0, stream,
                     a2, aux1_w, aux1_b, a3);
  hipLaunchKernelGGL(g_kernel, dim3(5, NB, 9), dim3(384), 0, stream,
                     a3, inx_w, Gbuf);
  hipLaunchKernelGGL(causal_kernel, dim3(NBLK), dim3(256), 0, stream,
                     audio, pk_causal, causal_b, h_all /* slab 0 = h_0 */);

  const int dils[9] = {1, 6, 36, 1, 6, 36, 1, 6, 36};
  for (int l = 0; l < 9; l++) {
    const unsigned short* hin = h_all + (size_t)l*HS;
    unsigned short* hout      = (l == 8) ? h_all : h_all + (size_t)(l+1)*HS;
    if (dils[l] == 36) {
      hipLaunchKernelGGL(layer_d_kernel, dim3(NBLK), dim3(256), 0, stream,
                         hin, hout,
                         pk_dilh + (size_t)l*6*6*24*64*8,
                         dilh_b + (size_t)l*384,
                         Gbuf + (size_t)l*NB*TAUX*384,
                         Cbuf + (size_t)l*384,
                         up_w);
    } else {
      hipLaunchKernelGGL(layer_u_kernel, dim3(NBLK), dim3(256), 0, stream,
                         dils[l], hin, hout,
                         pk_dilh + (size_t)l*6*6*24*64*8,
                         dilh_b + (size_t)l*384,
                         Gbuf + (size_t)l*NB*TAUX*384,
                         Cbuf + (size_t)l*384,
                         up_w);
    }
  }

  hipLaunchKernelGGL(skipsum_kernel, dim3(NBLK), dim3(256), 0, stream,
                     h_all, pk_skip, skip_b, sbuf);
  hipLaunchKernelGGL(out_kernel, dim3(NBLK), dim3(256), 0, stream,
                     sbuf, pk_out1, out1_b, pk_out2, out2_b, (float*)d_out);
}

// Round 12
// 904.473 us; speedup vs baseline: 1.3172x; 1.2622x over previous
//
#include <hip/hip_runtime.h>

#define TLEN 8249
#define TPAD 8320          // 130*64
#define NTILES 130
#define NB 4
#define NAUX 54
#define NQ 256
#define HID 192
#define NSKIP 256
#define KW 6
#define UPF 110
#define TAUX 75
#define PADR 180           // 5*36 max left reach of dilated conv
#define HROWS (PADR + TPAD)

typedef __attribute__((ext_vector_type(8))) short bf16x8v;
typedef __attribute__((ext_vector_type(4))) float f32x4;

__device__ __forceinline__ unsigned short f2bf(float f) {
  unsigned int u = __float_as_uint(f);
  u += 0x7FFFu + ((u >> 16) & 1u);   // RNE
  return (unsigned short)(u >> 16);
}

__device__ __forceinline__ f32x4 mfma16(bf16x8v a, bf16x8v b, f32x4 c) {
  return __builtin_amdgcn_mfma_f32_16x16x32_bf16(a, b, c, 0, 0, 0);
}

// ---------------- weight prepack (MFMA fragment order) + C vector ----------
__global__ void prepack_kernel(
    const float* causal_w, const float* dilh_w, const float* skip_w,
    const float* out1_w, const float* out2_w,
    const float* inx_w, const float* inx_b, const float* up_b,
    unsigned short* pk_causal, unsigned short* pk_dilh, unsigned short* pk_skip,
    unsigned short* pk_out1, unsigned short* pk_out2, float* Cbuf)
{
  int i = blockIdx.x * blockDim.x + threadIdx.x;
  if (i < 9*6*6*24*64*8) {            // dilh: [l][tap][kc6][nf24][lane][8]
    int t = i;
    int j = t & 7; t >>= 3;
    int lane = t & 63; t >>= 6;
    int nf = t % 24; t /= 24;
    int kc = t % 6; t /= 6;
    int tap = t % 6; t /= 6;
    int l = t;
    int oc = nf*16 + (lane & 15);
    int ic = kc*32 + ((lane >> 4) << 3) + j;
    pk_dilh[i] = f2bf(dilh_w[((l*384 + oc)*HID + ic)*KW + tap]);
  }
  if (i < 6*8*12*64*8) {              // causal: [tap][kc8][nf12][lane][8]
    int t = i;
    int j = t & 7; t >>= 3;
    int lane = t & 63; t >>= 6;
    int nf = t % 12; t /= 12;
    int kc = t % 8; t /= 8;
    int tap = t;
    int oc = nf*16 + (lane & 15);
    int ic = kc*32 + ((lane >> 4) << 3) + j;
    pk_causal[i] = f2bf(causal_w[(oc*NQ + ic)*KW + tap]);
  }
  if (i < 9*6*16*64*8) {              // skip: [l][kc6][nf16][lane][8]
    int t = i;
    int j = t & 7; t >>= 3;
    int lane = t & 63; t >>= 6;
    int nf = t % 16; t /= 16;
    int kc = t % 6; t /= 6;
    int l = t;
    int sc = nf*16 + (lane & 15);
    int ic = kc*32 + ((lane >> 4) << 3) + j;
    pk_skip[i] = f2bf(skip_w[(l*NSKIP + sc)*HID + ic]);
  }
  if (i < 8*16*64*8) {                // out1/out2: [kc8][nf16][lane][8]
    int t = i;
    int j = t & 7; t >>= 3;
    int lane = t & 63; t >>= 6;
    int nf = t % 16; t /= 16;
    int kc = t;
    int oq = nf*16 + (lane & 15);
    int sc = kc*32 + ((lane >> 4) << 3) + j;
    pk_out1[i] = f2bf(out1_w[oq*NSKIP + sc]);
    pk_out2[i] = f2bf(out2_w[oq*NQ + sc]);
  }
  if (i < 9*384) {                    // C[l][oc] = up_b*rowsum(inx_w)+inx_b
    int l = i / 384, oc = i % 384;
    const float* wr = inx_w + (l*384 + oc)*486;
    float s = 0.f;
    for (int c = 0; c < 486; c++) s += wr[c];
    Cbuf[i] = up_b[0]*s + inx_b[i];
  }
}

// ---------------- zero the 180-row causal pads of all 9 h slabs ------------
__global__ void zpad_kernel(unsigned short* h_all) {
  int i = blockIdx.x*blockDim.x + threadIdx.x;
  if (i < 9*NB*PADR*HID) {
    int slab = i / (NB*PADR*HID), r = i % (NB*PADR*HID);
    int b = r / (PADR*HID), rr = r % (PADR*HID);
    h_all[((size_t)slab*NB + b)*HROWS*HID + rr] = 0;
  }
}

// ---------------- tiny aux chain (all fp32) --------------------------------
__global__ void aux1_kernel(const float* aux, const float* w, const float* bias, float* a1) {
  int q = blockIdx.x, b = blockIdx.y, co = threadIdx.x;
  if (co >= NAUX) return;
  float acc = bias[co];
  for (int ci = 0; ci < NAUX; ci++)
    acc += w[co*NAUX + ci] * aux[(b*NAUX + ci)*TAUX + q];
  a1[(b*NAUX + co)*TAUX + q] = acc;
}

__global__ void aux2_kernel(const float* a1, const float* w, const float* bias, float* a2) {
  __shared__ float s[3][NAUX];
  int q = blockIdx.x, b = blockIdx.y, tid = threadIdx.x;
  for (int i = tid; i < 3*NAUX; i += blockDim.x) {
    int k = i / NAUX, c = i % NAUX;
    int qq = q - 1 + k;
    s[k][c] = (qq >= 0 && qq < TAUX) ? a1[(b*NAUX + c)*TAUX + qq] : 0.f;
  }
  __syncthreads();
  int co = tid;
  if (co >= 162) return;
  float acc = bias[co];
  for (int c = 0; c < NAUX; c++)
    #pragma unroll
    for (int k = 0; k < 3; k++)
      acc += w[(co*NAUX + c)*3 + k] * s[k][c];
  a2[(b*162 + co)*TAUX + q] = acc;
}

__global__ void aux3_kernel(const float* a2, const float* w, const float* bias, float* a3) {
  __shared__ float s[3][162];
  int q = blockIdx.x, b = blockIdx.y, tid = threadIdx.x;
  for (int i = tid; i < 3*162; i += blockDim.x) {
    int k = i / 162, c = i % 162;
    int qq = q + 3*(k - 1);
    s[k][c] = (qq >= 0 && qq < TAUX) ? a2[(b*162 + c)*TAUX + qq] : 0.f;
  }
  __syncthreads();
  int co = tid;
  if (co >= 486) return;
  float acc = bias[co];
  for (int c = 0; c < 162; c++)
    #pragma unroll
    for (int k = 0; k < 3; k++)
      acc += w[(co*162 + c)*3 + k] * s[k][c];
  a3[(b*486 + co)*TAUX + q] = acc;
}

// ---------------- G[l][b][q][oc] = sum_c inx_w[l][oc][c] * a3[b][c][q] -----
__global__ void g_kernel(const float* a3, const float* inx_w, float* G) {
  __shared__ float s[486][15];
  int q0 = blockIdx.x * 15, b = blockIdx.y, l = blockIdx.z;
  int tid = threadIdx.x;
  for (int i = tid; i < 486*15; i += 384) {
    int c = i / 15, qq = i % 15;
    s[c][qq] = a3[(b*486 + c)*TAUX + q0 + qq];
  }
  __syncthreads();
  int oc = tid;
  float acc[15];
  #pragma unroll
  for (int qq = 0; qq < 15; qq++) acc[qq] = 0.f;
  const float* wrow = inx_w + (l*384 + oc)*486;
  for (int c = 0; c < 486; c++) {
    float w = wrow[c];
    #pragma unroll
    for (int qq = 0; qq < 15; qq++) acc[qq] += w * s[c][qq];
  }
  for (int qq = 0; qq < 15; qq++)
    G[((size_t)(l*NB + b)*TAUX + q0 + qq)*384 + oc] = acc[qq];
}

// ---------------- causal conv (256ch K=6) + softsign -> h0 (bf16) ----------
__global__ __launch_bounds__(256, 2)
void causal_kernel(const float* audio, const unsigned short* pk, const float* cb,
                   unsigned short* hbf)
{
  __shared__ __align__(16) unsigned short sA[72*264];   // [t_win][ic pad264]
  int b = blockIdx.y, t0 = blockIdx.x*64, tid = threadIdx.x;
  int wv = tid >> 6, lane = tid & 63, lanelo = lane & 15;

  for (int i = tid; i < 72*256; i += 256) {   // stage audio tile, bf16
    int ic = i / 72, tt = i % 72;
    int t = t0 - 5 + tt;
    float v = (t >= 0 && t < TLEN) ? audio[(size_t)(b*NQ + ic)*TLEN + t] : 0.f;
    sA[tt*264 + ic] = f2bf(v);
  }
  __syncthreads();

  f32x4 acc[4][3];
  f32x4 z4 = {0.f, 0.f, 0.f, 0.f};
  #pragma unroll
  for (int m = 0; m < 4; m++)
    #pragma unroll
    for (int i = 0; i < 3; i++) acc[m][i] = z4;

  for (int tap = 0; tap < 6; tap++) {
    for (int kc = 0; kc < 8; kc++) {
      bf16x8v A[4];
      int ko = kc*32 + ((lane >> 4) << 3);
      #pragma unroll
      for (int m = 0; m < 4; m++)
        A[m] = *(const bf16x8v*)&sA[(m*16 + lanelo + tap)*264 + ko];
      #pragma unroll
      for (int i = 0; i < 3; i++) {
        int nf = wv*3 + i;
        bf16x8v Bf = *(const bf16x8v*)&pk[(size_t)((((tap*8) + kc)*12 + nf)*64 + lane)*8];
        #pragma unroll
        for (int m = 0; m < 4; m++) acc[m][i] = mfma16(A[m], Bf, acc[m][i]);
      }
    }
  }

  #pragma unroll
  for (int m = 0; m < 4; m++)
    #pragma unroll
    for (int i = 0; i < 3; i++) {
      int oc = (wv*3 + i)*16 + lanelo;
      float bias = cb[oc];
      #pragma unroll
      for (int r = 0; r < 4; r++) {
        int tl = m*16 + ((lane >> 4) << 2) + r;
        int t = t0 + tl;
        float v = acc[m][i][r] + bias;
        float h0 = v / (1.f + fabsf(v));
        hbf[(size_t)(b*HROWS + t + PADR)*HID + oc] = f2bf(h0);
      }
    }
}

// ---------------- per-layer: dilh conv (MFMA) -> gate -> h_{l+1} -----------
// 256 thr = 4 waves, 1 M-group x 4 N-groups, M=64, B-frags read once/block.
// dil 1/6: union window staged once -> 1 barrier. dil 36: per-tap dbuf strips.
__global__ __launch_bounds__(256, 3)
void layer_kernel(int dil,
                  const unsigned short* __restrict__ hin,
                  unsigned short* __restrict__ hout,
                  const unsigned short* __restrict__ pk_dilh_l,
                  const float* __restrict__ dilh_b_l,
                  const float* __restrict__ Gl, const float* __restrict__ Cl,
                  const float* __restrict__ up_w)
{
  __shared__ __align__(16) unsigned short hs[2][64*192];   // 49152 B flat
  int b = blockIdx.y, t0 = blockIdx.x*64, tid = threadIdx.x;
  int wv = tid >> 6, lane = tid & 63, lanelo = lane & 15, lanehi = lane >> 4;

  const size_t hbase = (size_t)b * HROWS * HID;
  int rowbase0 = t0 - 5*dil + PADR;            // >= 0 always

  f32x4 accz[4][3], acct[4][3];
  f32x4 z4 = {0.f, 0.f, 0.f, 0.f};
  #pragma unroll
  for (int m = 0; m < 4; m++)
    #pragma unroll
    for (int i = 0; i < 3; i++) { accz[m][i] = z4; acct[m][i] = z4; }

  const unsigned short* holdbuf;
  int holdoff;
  unsigned short* flat = &hs[0][0];

  if (dil != 36) {
    // ---- union-window path: W rows staged once, single barrier ----
    int W = 64 + 5*dil;                        // 69 or 94
    for (int c = tid; c < W*24; c += 256) {
      int row = c/24, cbk = c%24;
      uint4 v = *(const uint4*)&hin[hbase + (size_t)(rowbase0+row)*HID + cbk*8];
      *(uint4*)&flat[row*192 + ((cbk ^ (row&7))<<3)] = v;
    }
    __syncthreads();
    for (int tap = 0; tap < 6; tap++) {
      #pragma unroll
      for (int kc = 0; kc < 6; kc++) {
        bf16x8v A[4];
        #pragma unroll
        for (int m = 0; m < 4; m++) {
          int r = m*16 + lanelo + tap*dil;
          int cbk = kc*4 + lanehi;
          A[m] = *(const bf16x8v*)&flat[r*192 + ((cbk ^ (r&7))<<3)];
        }
        #pragma unroll
        for (int i = 0; i < 3; i++) {
          const unsigned short* bp =
              &pk_dilh_l[(size_t)(((tap*6 + kc)*24 + wv*3 + i)*64 + lane)*8];
          bf16x8v Bz = *(const bf16x8v*)bp;
          bf16x8v Bt = *(const bf16x8v*)(bp + 12*512);
          #pragma unroll
          for (int m = 0; m < 4; m++) {
            accz[m][i] = mfma16(A[m], Bz, accz[m][i]);
            acct[m][i] = mfma16(A[m], Bt, acct[m][i]);
          }
        }
      }
    }
    holdbuf = flat; holdoff = 5*dil;
  } else {
    // ---- per-tap strip path (dil=36), double-buffered ----
    uint4 st[6];
    #pragma unroll
    for (int j = 0; j < 6; j++) {
      int c = tid + j*256, row = c/24, cbk = c%24;
      st[j] = *(const uint4*)&hin[hbase + (size_t)(rowbase0+row)*HID + cbk*8];
    }
    #pragma unroll
    for (int j = 0; j < 6; j++) {
      int c = tid + j*256, row = c/24, cbk = c%24;
      *(uint4*)&hs[0][row*192 + ((cbk ^ (row&7))<<3)] = st[j];
    }
    for (int tap = 0; tap < 6; tap++) {
      __syncthreads();
      if (tap < 5) {
        int rb = rowbase0 + (tap+1)*36;
        #pragma unroll
        for (int j = 0; j < 6; j++) {
          int c = tid + j*256, row = c/24, cbk = c%24;
          st[j] = *(const uint4*)&hin[hbase + (size_t)(rb+row)*HID + cbk*8];
        }
      }
      const unsigned short* bufc = hs[tap & 1];
      #pragma unroll
      for (int kc = 0; kc < 6; kc++) {
        bf16x8v A[4];
        #pragma unroll
        for (int m = 0; m < 4; m++) {
          int r = m*16 + lanelo;
          int cbk = kc*4 + lanehi;
          A[m] = *(const bf16x8v*)&bufc[r*192 + ((cbk ^ (r&7))<<3)];
        }
        #pragma unroll
        for (int i = 0; i < 3; i++) {
          const unsigned short* bp =
              &pk_dilh_l[(size_t)(((tap*6 + kc)*24 + wv*3 + i)*64 + lane)*8];
          bf16x8v Bz = *(const bf16x8v*)bp;
          bf16x8v Bt = *(const bf16x8v*)(bp + 12*512);
          #pragma unroll
          for (int m = 0; m < 4; m++) {
            accz[m][i] = mfma16(A[m], Bz, accz[m][i]);
            acct[m][i] = mfma16(A[m], Bt, acct[m][i]);
          }
        }
      }
      if (tap < 5) {
        unsigned short* bufn = hs[(tap+1) & 1];
        #pragma unroll
        for (int j = 0; j < 6; j++) {
          int c = tid + j*256, row = c/24, cbk = c%24;
          *(uint4*)&bufn[row*192 + ((cbk ^ (row&7))<<3)] = st[j];
        }
      }
    }
    holdbuf = &hs[1][0]; holdoff = 0;   // tap5 strip = h_old rows
  }

  // gate: z = sigmoid(xz), h_new = (1-z)*tanh(xt) + z*h_old (h_old from LDS)
  float izc[3], itc[3], bzc[3], btc[3];
  #pragma unroll
  for (int i = 0; i < 3; i++) {
    int ocz = (wv*3 + i)*16 + lanelo;
    izc[i] = Cl[ocz];       itc[i] = Cl[192 + ocz];
    bzc[i] = dilh_b_l[ocz]; btc[i] = dilh_b_l[192 + ocz];
  }
  #pragma unroll
  for (int m = 0; m < 4; m++) {
    #pragma unroll
    for (int r = 0; r < 4; r++) {
      int tl = m*16 + (lanehi << 2) + r;
      int t = t0 + tl;
      int hr = tl + holdoff;
      int tp1 = t + 1;
      int q = tp1 / UPF; if (q > TAUX - 1) q = TAUX - 1;
      int ui = tp1 - q*UPF; if (ui > UPF - 1) ui = UPF - 1;
      float u = up_w[ui];
      const float* Gb = Gl + (size_t)(b*TAUX + q)*384;
      #pragma unroll
      for (int i = 0; i < 3; i++) {
        int ocz = (wv*3 + i)*16 + lanelo;
        float iz = u*Gb[ocz]       + izc[i];
        float it = u*Gb[192 + ocz] + itc[i];
        float xz = (accz[m][i][r] + bzc[i]) * iz;
        float xt = (acct[m][i][r] + btc[i]) * it;
        float z  = 1.f / (1.f + __expf(-xz));
        float e2 = __expf(2.f*xt);
        float th = 1.f - 2.f/(e2 + 1.f);
        int cbh = ocz >> 3, jh = ocz & 7;
        unsigned short hob = holdbuf[hr*192 + ((cbh ^ (hr&7))<<3) + jh];
        float hold = __uint_as_float(((unsigned int)hob) << 16);
        float hn = (1.f - z)*th + z*hold;
        hout[hbase + (size_t)(t + PADR)*HID + ocz] = f2bf(hn);
      }
    }
  }
}

// ---------------- fused tail: skipsum -> relu -> out1 -> relu -> out2 ------
// 256 thr = 4 waves, M=64, (256,3). s-tile stays in LDS (no sbuf round-trip).
__global__ __launch_bounds__(256, 3)
void tail_kernel(const unsigned short* __restrict__ h_all,
                 const unsigned short* __restrict__ pk_skip,
                 const float* __restrict__ skip_b,
                 const unsigned short* __restrict__ pk1, const float* __restrict__ b1,
                 const unsigned short* __restrict__ pk2, const float* __restrict__ b2,
                 float* __restrict__ dout)
{
  __shared__ __align__(16) unsigned short ss[2][64*192];   // 49152 B
  int b = blockIdx.y, t0 = blockIdx.x*64, tid = threadIdx.x;
  int wv = tid >> 6, lane = tid & 63, lanelo = lane & 15, lanehi = lane >> 4;
  const size_t HS = (size_t)NB * HROWS * HID;
  f32x4 z4 = {0.f, 0.f, 0.f, 0.f};

  auto hsrc = [&](int l) {
    int slab = (l == 8) ? 0 : (l + 1);
    return h_all + (size_t)slab*HS + (size_t)b*HROWS*HID + (size_t)(t0 + PADR)*HID;
  };

  uint4 st[6];
  {  // prologue: stage layer 0
    const unsigned short* src = hsrc(0);
    #pragma unroll
    for (int j = 0; j < 6; j++) {
      int c = tid + j*256, row = c/24, cbk = c%24;
      st[j] = *(const uint4*)&src[(size_t)row*HID + cbk*8];
    }
    #pragma unroll
    for (int j = 0; j < 6; j++) {
      int c = tid + j*256, row = c/24, cbk = c%24;
      *(uint4*)&ss[0][row*192 + ((cbk ^ (row&7))<<3)] = st[j];
    }
  }

  f32x4 acc[4][4];
  #pragma unroll
  for (int m = 0; m < 4; m++)
    #pragma unroll
    for (int i = 0; i < 4; i++) acc[m][i] = z4;

  for (int l = 0; l < 9; l++) {
    __syncthreads();
    if (l < 8) {           // T14: issue next-layer loads over this layer's MFMAs
      const unsigned short* src = hsrc(l + 1);
      #pragma unroll
      for (int j = 0; j < 6; j++) {
        int c = tid + j*256, row = c/24, cbk = c%24;
        st[j] = *(const uint4*)&src[(size_t)row*HID + cbk*8];
      }
    }
    const unsigned short* bufc = ss[l & 1];
    #pragma unroll
    for (int kc = 0; kc < 6; kc++) {
      bf16x8v A[4];
      #pragma unroll
      for (int m = 0; m < 4; m++) {
        int r = m*16 + lanelo;
        int cbk = kc*4 + lanehi;
        A[m] = *(const bf16x8v*)&bufc[r*192 + ((cbk ^ (r&7))<<3)];
      }
      #pragma unroll
      for (int i = 0; i < 4; i++) {
        bf16x8v Bf = *(const bf16x8v*)
            &pk_skip[(size_t)(((l*6 + kc)*16 + wv*4 + i)*64 + lane)*8];
        #pragma unroll
        for (int m = 0; m < 4; m++) acc[m][i] = mfma16(A[m], Bf, acc[m][i]);
      }
    }
    if (l < 8) {
      unsigned short* bufn = ss[(l+1) & 1];
      #pragma unroll
      for (int j = 0; j < 6; j++) {
        int c = tid + j*256, row = c/24, cbk = c%24;
        *(uint4*)&bufn[row*192 + ((cbk ^ (row&7))<<3)] = st[j];
      }
    }
  }
  __syncthreads();   // all skip A-reads done; reuse ss as [64][264] s-tile

  unsigned short* tile = &ss[0][0];
  #pragma unroll
  for (int i = 0; i < 4; i++) {
    int sc = (wv*4 + i)*16 + lanelo;
    float bias = 0.f;
    #pragma unroll
    for (int l = 0; l < 9; l++) bias += skip_b[l*NSKIP + sc];
    #pragma unroll
    for (int m = 0; m < 4; m++) {
      #pragma unroll
      for (int r = 0; r < 4; r++) {
        int tl = m*16 + (lanehi << 2) + r;
        tile[tl*264 + sc] = f2bf(fmaxf(acc[m][i][r] + bias, 0.f));
      }
    }
  }
  __syncthreads();

  // out1: [64][256] x [256][256]
  #pragma unroll
  for (int m = 0; m < 4; m++)
    #pragma unroll
    for (int i = 0; i < 4; i++) acc[m][i] = z4;
  for (int kc = 0; kc < 8; kc++) {
    bf16x8v A[4];
    int ko = kc*32 + (lanehi << 3);
    #pragma unroll
    for (int m = 0; m < 4; m++)
      A[m] = *(const bf16x8v*)&tile[(m*16 + lanelo)*264 + ko];
    #pragma unroll
    for (int i = 0; i < 4; i++) {
      bf16x8v Bf = *(const bf16x8v*)&pk1[(size_t)((kc*16 + wv*4 + i)*64 + lane)*8];
      #pragma unroll
      for (int m = 0; m < 4; m++) acc[m][i] = mfma16(A[m], Bf, acc[m][i]);
    }
  }
  __syncthreads();
  #pragma unroll
  for (int m = 0; m < 4; m++)
    #pragma unroll
    for (int i = 0; i < 4; i++) {
      int oq = (wv*4 + i)*16 + lanelo;
      float bias = b1[oq];
      #pragma unroll
      for (int r = 0; r < 4; r++) {
        int tl = m*16 + (lanehi << 2) + r;
        tile[tl*264 + oq] = f2bf(fmaxf(acc[m][i][r] + bias, 0.f));
      }
    }
  __syncthreads();

  // out2: [64][256] x [256][256]
  #pragma unroll
  for (int m = 0; m < 4; m++)
    #pragma unroll
    for (int i = 0; i < 4; i++) acc[m][i] = z4;
  for (int kc = 0; kc < 8; kc++) {
    bf16x8v A[4];
    int ko = kc*32 + (lanehi << 3);
    #pragma unroll
    for (int m = 0; m < 4; m++)
      A[m] = *(const bf16x8v*)&tile[(m*16 + lanelo)*264 + ko];
    #pragma unroll
    for (int i = 0; i < 4; i++) {
      bf16x8v Bf = *(const bf16x8v*)&pk2[(size_t)((kc*16 + wv*4 + i)*64 + lane)*8];
      #pragma unroll
      for (int m = 0; m < 4; m++) acc[m][i] = mfma16(A[m], Bf, acc[m][i]);
    }
  }
  // two fp32 half-tiles [32][260] aliasing ss, coalesced dout writes
  float* so2 = (float*)&ss[0][0];
  #pragma unroll
  for (int p = 0; p < 2; p++) {
    __syncthreads();
    #pragma unroll
    for (int mm = 0; mm < 2; mm++) {
      int m = p*2 + mm;
      #pragma unroll
      for (int i = 0; i < 4; i++) {
        int oq = (wv*4 + i)*16 + lanelo;
        float bias = b2[oq];
        #pragma unroll
        for (int r = 0; r < 4; r++) {
          int lr = mm*16 + (lanehi << 2) + r;
          so2[lr*260 + oq] = acc[m][i][r] + bias;
        }
      }
    }
    __syncthreads();
    #pragma unroll
    for (int j = 0; j < 8; j++) {
      int c = tid + j*256, row = c >> 6, ch = c & 63;
      int t = t0 + p*32 + row;
      if (t < TLEN) {
        uint4 v = *(const uint4*)&so2[row*260 + ch*4];
        *(uint4*)&dout[(size_t)(b*TLEN + t)*NQ + ch*4] = v;
      }
    }
  }
}

// ---------------------------------------------------------------------------
extern "C" void kernel_launch(void* const* d_in, const int* in_sizes, int n_in,
                              void* d_out, int out_size, void* d_ws, size_t ws_size,
                              hipStream_t stream)
{
  const float* audio      = (const float*)d_in[0];
  const float* aux        = (const float*)d_in[1];
  const float* scale_in_w = (const float*)d_in[2];
  const float* scale_in_b = (const float*)d_in[3];
  const float* aux0_w     = (const float*)d_in[4];
  const float* aux0_b     = (const float*)d_in[5];
  const float* aux1_w     = (const float*)d_in[6];
  const float* aux1_b     = (const float*)d_in[7];
  const float* up_w       = (const float*)d_in[8];
  const float* up_b       = (const float*)d_in[9];
  const float* causal_w   = (const float*)d_in[10];
  const float* causal_b   = (const float*)d_in[11];
  const float* inx_w      = (const float*)d_in[12];
  const float* inx_b      = (const float*)d_in[13];
  const float* dilh_w     = (const float*)d_in[14];
  const float* dilh_b     = (const float*)d_in[15];
  const float* skip_w     = (const float*)d_in[16];
  const float* skip_b     = (const float*)d_in[17];
  const float* out1_w     = (const float*)d_in[18];
  const float* out1_b     = (const float*)d_in[19];
  const float* out2_w     = (const float*)d_in[20];
  const float* out2_b     = (const float*)d_in[21];

  char* ws = (char*)d_ws;
  size_t off = 0;
  auto alloc = [&](size_t bytes) -> void* {
    void* p = ws + off;
    off += (bytes + 255) & ~(size_t)255;
    return p;
  };
  unsigned short* pk_causal = (unsigned short*)alloc((size_t)6*8*12*64*8*2);
  unsigned short* pk_dilh   = (unsigned short*)alloc((size_t)9*6*6*24*64*8*2);
  unsigned short* pk_skip   = (unsigned short*)alloc((size_t)9*6*16*64*8*2);
  unsigned short* pk_out1   = (unsigned short*)alloc((size_t)8*16*64*8*2);
  unsigned short* pk_out2   = (unsigned short*)alloc((size_t)8*16*64*8*2);
  float* Cbuf    = (float*)alloc((size_t)9*384*4);
  float* a1      = (float*)alloc((size_t)NB*NAUX*TAUX*4);
  float* a2      = (float*)alloc((size_t)NB*162*TAUX*4);
  float* a3      = (float*)alloc((size_t)NB*486*TAUX*4);
  float* Gbuf    = (float*)alloc((size_t)9*NB*TAUX*384*4);
  const size_t HS = (size_t)NB*HROWS*HID;
  unsigned short* h_all = (unsigned short*)alloc((size_t)9*HS*2);  // slabs 0..8

  hipLaunchKernelGGL(prepack_kernel, dim3((9*6*6*24*64*8 + 255)/256), dim3(256), 0, stream,
                     causal_w, dilh_w, skip_w, out1_w, out2_w, inx_w, inx_b, up_b,
                     pk_causal, pk_dilh, pk_skip, pk_out1, pk_out2, Cbuf);
  hipLaunchKernelGGL(zpad_kernel, dim3((9*NB*PADR*HID + 255)/256), dim3(256), 0, stream,
                     h_all);
  hipLaunchKernelGGL(aux1_kernel, dim3(TAUX, NB), dim3(64), 0, stream,
                     aux, scale_in_w, scale_in_b, a1);
  hipLaunchKernelGGL(aux2_kernel, dim3(TAUX, NB), dim3(192), 0, stream,
                     a1, aux0_w, aux0_b, a2);
  hipLaunchKernelGGL(aux3_kernel, dim3(TAUX, NB), dim3(512), 0, stream,
                     a2, aux1_w, aux1_b, a3);
  hipLaunchKernelGGL(g_kernel, dim3(5, NB, 9), dim3(384), 0, stream,
                     a3, inx_w, Gbuf);
  hipLaunchKernelGGL(causal_kernel, dim3(NTILES, NB), dim3(256), 0, stream,
                     audio, pk_causal, causal_b, h_all /* slab 0 = h_0 */);

  const int dils[9] = {1, 6, 36, 1, 6, 36, 1, 6, 36};
  for (int l = 0; l < 9; l++) {
    const unsigned short* hin = h_all + (size_t)l*HS;
    unsigned short* hout      = (l == 8) ? h_all : h_all + (size_t)(l+1)*HS;
    hipLaunchKernelGGL(layer_kernel, dim3(NTILES, NB), dim3(256), 0, stream,
                       dils[l], hin, hout,
                       pk_dilh + (size_t)l*6*6*24*64*8,
                       dilh_b + (size_t)l*384,
                       Gbuf + (size_t)l*NB*TAUX*384,
                       Cbuf + (size_t)l*384,
                       up_w);
  }

  hipLaunchKernelGGL(tail_kernel, dim3(NTILES, NB), dim3(256), 0, stream,
                     h_all, pk_skip, skip_b, pk_out1, out1_b, pk_out2, out2_b,
                     (float*)d_out);
}